// Round 9
// baseline (1859.442 us; speedup 1.0000x reference)
//
#include <hip/hip_runtime.h>
#include <hip/hip_fp16.h>

constexpr int NU = 150000;
constexpr int NR = 150000;
constexpr int Hc = 64;
constexpr int UF = 58;
constexpr int RF = 128;
constexpr long EE = 2000000;
constexpr long ELc = 500000;
constexpr int NTOT = NU + NR;            // combined ids: [0,NR)=recipes, [NR,NTOT)=users
constexpr int BKT = 256;                 // nodes per bucket
constexpr int NB_R = (NR + BKT - 1) / BKT;   // 586
constexpr int NB_U = (NU + BKT - 1) / BKT;   // 586
constexpr int NBKT = NB_R + NB_U;            // 1172
constexpr int CHUNK = 4096;
constexpr int NCHUNK = (int)((EE + CHUNK - 1) / CHUNK);  // 489
constexpr long N8 = (long)NU * 8;        // elements per channel-group slice

__device__ inline float rdlane(float v, int l) {
    return __uint_as_float(__builtin_amdgcn_readlane(__float_as_uint(v), l));
}

// ---- weight pre-transpose: d[k*64+o] = s[o*F+k] (10 small matrices) ----
struct TP { const float* s; float* d; int F; };
struct TP10 { TP m[10]; };
__global__ void transpose_kernel(TP10 p) {
    TP t = p.m[blockIdx.x];
    for (int idx = threadIdx.x; idx < t.F * Hc; idx += blockDim.x) {
        int k = idx >> 6, o = idx & 63;
        t.d[idx] = t.s[o * t.F + k];
    }
}

// ---- CSR build, pass 0: per-bucket edge counts (LDS-binned) ----
__global__ void bucket_count_kernel(const int* __restrict__ ei, int* __restrict__ bcnt) {
    __shared__ int lc[NBKT];
    for (int i = threadIdx.x; i < NBKT; i += 256) lc[i] = 0;
    __syncthreads();
    long e0 = (long)blockIdx.x * CHUNK;
    for (int k = threadIdx.x; k < CHUNK; k += 256) {
        long e = e0 + k;
        if (e < EE) {
            int u = ei[e], r = ei[EE + e];
            atomicAdd(&lc[r >> 8], 1);
            atomicAdd(&lc[NB_R + (u >> 8)], 1);
        }
    }
    __syncthreads();
    for (int i = threadIdx.x; i < NBKT; i += 256)
        if (lc[i]) atomicAdd(&bcnt[i], lc[i]);
}

// ---- pass 1: exclusive scan over NBKT bucket counts (single block) ----
__global__ void bucket_scan_kernel(const int* __restrict__ bcnt, int* __restrict__ bbase,
                                   int* __restrict__ bcur) {
    __shared__ int part[256];
    constexpr int PER = (NBKT + 255) / 256;   // 5
    int t = threadIdx.x;
    int loc[PER];
    int sum = 0;
    for (int j = 0; j < PER; ++j) {
        int i = t * PER + j;
        int v = (i < NBKT) ? bcnt[i] : 0;
        loc[j] = sum;
        sum += v;
    }
    part[t] = sum;
    __syncthreads();
    for (int off = 1; off < 256; off <<= 1) {
        int v = (t >= off) ? part[t - off] : 0;
        __syncthreads();
        part[t] += v;
        __syncthreads();
    }
    int pre = (t == 0) ? 0 : part[t - 1];
    for (int j = 0; j < PER; ++j) {
        int i = t * PER + j;
        if (i < NBKT) {
            int b = pre + loc[j];
            bbase[i] = b;
            bcur[i] = b;
        }
    }
    if (t == 255) bbase[NBKT] = part[255];
}

// ---- pass 2: chunked-reservation record scatter (4B records: local8|src18) ----
__global__ void scatter_records_kernel(const int* __restrict__ ei, int* __restrict__ bcur,
                                       int* __restrict__ rec) {
    __shared__ int lc[NBKT];
    for (int i = threadIdx.x; i < NBKT; i += 256) lc[i] = 0;
    __syncthreads();
    long e0 = (long)blockIdx.x * CHUNK;
    for (int k = threadIdx.x; k < CHUNK; k += 256) {
        long e = e0 + k;
        if (e < EE) {
            int u = ei[e], r = ei[EE + e];
            atomicAdd(&lc[r >> 8], 1);
            atomicAdd(&lc[NB_R + (u >> 8)], 1);
        }
    }
    __syncthreads();
    for (int i = threadIdx.x; i < NBKT; i += 256) {
        int c = lc[i];
        lc[i] = c ? atomicAdd(&bcur[i], c) : 0;   // reserve contiguous range
    }
    __syncthreads();
    for (int k = threadIdx.x; k < CHUNK; k += 256) {
        long e = e0 + k;
        if (e < EE) {
            int u = ei[e], r = ei[EE + e];
            int p1 = atomicAdd(&lc[r >> 8], 1);
            rec[p1] = ((r & 255) << 18) | u;
            int p2 = atomicAdd(&lc[NB_R + (u >> 8)], 1);
            rec[p2] = ((u & 255) << 18) | r;
        }
    }
}

// ---- pass 3: per-bucket counting sort -> adj (+ per-node base/cnt) ----
__global__ void build_adj_kernel(const int* __restrict__ rec, const int* __restrict__ bbase,
                                 int* __restrict__ adj, int* __restrict__ base,
                                 int* __restrict__ cnt) {
    __shared__ int c256[BKT];
    __shared__ int off256[BKT];
    int b = blockIdx.x;
    int s = bbase[b], e = bbase[b + 1];
    int t = threadIdx.x;
    c256[t] = 0;
    __syncthreads();
    for (int k = s + t; k < e; k += 256) atomicAdd(&c256[rec[k] >> 18], 1);
    __syncthreads();
    int v = c256[t];
    off256[t] = v;
    __syncthreads();
    for (int off = 1; off < 256; off <<= 1) {
        int x = (t >= off) ? off256[t - off] : 0;
        __syncthreads();
        off256[t] += x;
        __syncthreads();
    }
    int excl = off256[t] - v;
    bool isU = (b >= NB_R);
    int node = (isU ? (b - NB_R) : b) * BKT + t;
    int lim = isU ? NU : NR;
    if (node < lim) {
        int cid = isU ? (NR + node) : node;
        base[cid] = s + excl;
        cnt[cid] = v;
    }
    c256[t] = s + excl;    // cursors
    __syncthreads();
    for (int k = s + t; k < e; k += 256) {
        int rv = rec[k];
        int p = atomicAdd(&c256[rv >> 18], 1);
        adj[p] = rv & 0x3FFFF;
    }
}

// ---- node encoder: LDS weights, readlane broadcast, 4-way split chains ----
template <int F>
__global__ __launch_bounds__(256) void encode_kernel(
        const float* __restrict__ xin, const float* __restrict__ wT,
        const float* __restrict__ b, const float* __restrict__ emb,
        const int* __restrict__ nid, float* __restrict__ out, int N) {
    __shared__ float w[F * Hc];
    for (int idx = threadIdx.x; idx < F * Hc; idx += 256) w[idx] = wT[idx];
    __syncthreads();
    int t = threadIdx.x & 63;
    int wave = (int)((blockIdx.x * blockDim.x + threadIdx.x) >> 6);
    int nwaves = (gridDim.x * blockDim.x) >> 6;
    float bv = b[t];
    for (int r = wave; r < N; r += nwaves) {
        float xv0 = (t < F) ? xin[(long)r * F + t] : 0.0f;
        float xv1 = (F > 64) ? xin[(long)r * F + 64 + t] : 0.0f;
        float a0 = bv, a1 = 0.0f, a2 = 0.0f, a3 = 0.0f;
#pragma unroll
        for (int k = 0; k < F; ++k) {
            float s = (k < 64) ? rdlane(xv0, k) : rdlane(xv1, k - 64);
            float wv = w[k * Hc + t];
            if ((k & 3) == 0)      a0 = fmaf(s, wv, a0);
            else if ((k & 3) == 1) a1 = fmaf(s, wv, a1);
            else if ((k & 3) == 2) a2 = fmaf(s, wv, a2);
            else                   a3 = fmaf(s, wv, a3);
        }
        float acc = (a0 + a1) + (a2 + a3);
        acc += emb[(long)nid[r] * Hc + t];
        out[(long)r * Hc + t] = acc;
    }
}

// ---- dense pair (both relations, one dispatch): T = in@wl^T (fp16, GROUP-MAJOR
//      layout T[g][n][8] for the XCD-pinned gather); PRE = in@wr^T + br (f32). ----
__global__ __launch_bounds__(256) void dense2_pair_kernel(
        const float* inU, const float* wlTU, __half* ToutU,
        const float* wrTU, const float* brU, float* PREU,
        const float* inR, const float* wlTR, __half* ToutR,
        const float* wrTR, const float* brR, float* PRER) {
    __shared__ float w[Hc * 128];   // [k][0..63]=wl, [k][64..127]=wr
    int half = gridDim.x >> 1;
    bool isR = blockIdx.x >= half;
    const float* in  = isR ? inR : inU;
    const float* wlT = isR ? wlTR : wlTU;
    const float* wrT = isR ? wrTR : wrTU;
    const float* br  = isR ? brR : brU;
    __half* Tout = isR ? ToutR : ToutU;
    float* PRE   = isR ? PRER : PREU;
    for (int idx = threadIdx.x; idx < Hc * Hc; idx += 256) {
        int k = idx >> 6, o = idx & 63;
        w[k * 128 + o] = wlT[idx];
        w[k * 128 + 64 + o] = wrT[idx];
    }
    __syncthreads();
    int t = threadIdx.x & 63;
    long toff = (long)(t >> 3) * N8 + (t & 7);   // group-major T offset for this lane
    int wid = (int)((((long)blockIdx.x - (isR ? half : 0)) * 256 + threadIdx.x) >> 6);
    int nw = (half * 256) >> 6;
    float bv = br[t];
    for (int r = wid; r < NU; r += nw) {
        float xv = in[(long)r * Hc + t];
        float aA0 = 0.0f, aA1 = 0.0f, aB0 = bv, aB1 = 0.0f;
#pragma unroll
        for (int k = 0; k < Hc; k += 2) {
            float s0 = rdlane(xv, k);
            float s1 = rdlane(xv, k + 1);
            aA0 = fmaf(s0, w[k * 128 + t], aA0);
            aA1 = fmaf(s1, w[(k + 1) * 128 + t], aA1);
            aB0 = fmaf(s0, w[k * 128 + 64 + t], aB0);
            aB1 = fmaf(s1, w[(k + 1) * 128 + 64 + t], aB1);
        }
        Tout[toff + (long)r * 8] = __float2half(aA0 + aA1);
        PRE[(long)r * Hc + t] = aB0 + aB1;
    }
}

// ---- XCD-pinned channel-split gather (one side per dispatch):
//      block g = blockIdx.x & 7 handles channel-group g (2.4MB slice -> one XCD L2).
//      Wave per destination; lane = (channel-pair 0..3) x (neighbor-slot 0..15). ----
__global__ __launch_bounds__(256) void gather_xcd_kernel(
        const __half* __restrict__ Tg, float* __restrict__ io,
        const int* __restrict__ base, const int* __restrict__ cnt,
        const int* __restrict__ adj, int noff, int relu) {
    int l = threadIdx.x & 63;
    int cp = l & 3;          // channel pair within group
    int p = l >> 2;          // neighbor slot 0..15
    int g = blockIdx.x & 7;
    int r = (blockIdx.x >> 3) * 4 + (threadIdx.x >> 6);
    if (r >= NU) return;
    int b0 = base[noff + r], c = cnt[noff + r];
    const __half* T = Tg + (long)g * N8 + 2 * cp;
    float sx = 0.0f, sy = 0.0f;
    for (int j = p; j < c; j += 16) {
        int n = adj[b0 + j];
        float2 f = __half22float2(*(const __half2*)(T + (long)n * 8));
        sx += f.x; sy += f.y;
    }
    sx += __shfl_xor(sx, 4);  sy += __shfl_xor(sy, 4);
    sx += __shfl_xor(sx, 8);  sy += __shfl_xor(sy, 8);
    sx += __shfl_xor(sx, 16); sy += __shfl_xor(sy, 16);
    sx += __shfl_xor(sx, 32); sy += __shfl_xor(sy, 32);
    if (p == 0) {
        float inv = 1.0f / fmaxf((float)c, 1.0f);
        float* o = io + (long)r * Hc + g * 8 + 2 * cp;
        float2 cur = *(float2*)o;
        float ox = cur.x + sx * inv;
        float oy = cur.y + sy * inv;
        if (relu) { ox = fmaxf(ox, 0.0f); oy = fmaxf(oy, 0.0f); }
        *(float2*)o = make_float2(ox, oy);
    }
}

// ---- edge dot-product classifier ----
__global__ void edge_dot_kernel(const int* __restrict__ eli,
                                const float* __restrict__ HU2, const float* __restrict__ HR2,
                                float* __restrict__ out) {
    long gid = (long)blockIdx.x * blockDim.x + threadIdx.x;
    long e = gid >> 4;
    int t = (int)(gid & 15);
    if (e >= ELc) return;
    int a = eli[e], b = eli[ELc + e];
    float4 x = *(const float4*)(HU2 + (long)a * Hc + t * 4);
    float4 y = *(const float4*)(HR2 + (long)b * Hc + t * 4);
    float v = x.x * y.x + x.y * y.y + x.z * y.z + x.w * y.w;
    v += __shfl_xor(v, 1);
    v += __shfl_xor(v, 2);
    v += __shfl_xor(v, 4);
    v += __shfl_xor(v, 8);
    if (t == 0) out[e] = v;
}

extern "C" void kernel_launch(void* const* d_in, const int* in_sizes, int n_in,
                              void* d_out, int out_size, void* d_ws, size_t ws_size,
                              hipStream_t stream) {
    const float* x_user   = (const float*)d_in[0];
    const float* x_recipe = (const float*)d_in[1];
    const int*   user_nid = (const int*)d_in[2];
    const int*   rec_nid  = (const int*)d_in[3];
    const int*   edge_index = (const int*)d_in[4];
    const int*   edge_label = (const int*)d_in[5];
    const float* u_w   = (const float*)d_in[6];
    const float* u_b   = (const float*)d_in[7];
    const float* r_w   = (const float*)d_in[8];
    const float* r_b   = (const float*)d_in[9];
    const float* u_emb = (const float*)d_in[10];
    const float* r_emb = (const float*)d_in[11];
    const float* c1ra_wl = (const float*)d_in[12];
    const float* c1ra_bl = (const float*)d_in[13];
    const float* c1ra_wr = (const float*)d_in[14];
    const float* c1rv_wl = (const float*)d_in[15];
    const float* c1rv_bl = (const float*)d_in[16];
    const float* c1rv_wr = (const float*)d_in[17];
    const float* c2ra_wl = (const float*)d_in[18];
    const float* c2ra_bl = (const float*)d_in[19];
    const float* c2ra_wr = (const float*)d_in[20];
    const float* c2rv_wl = (const float*)d_in[21];
    const float* c2rv_bl = (const float*)d_in[22];
    const float* c2rv_wr = (const float*)d_in[23];

    float* ws = (float*)d_ws;
    const long NH = (long)NU * Hc;
    float* B0 = ws;            // XU -> PRE_U2 -> HU2
    float* B1 = B0 + NH;       // XR -> PRE_R2 -> HR2
    float* B2 = B1 + NH;       // rec alias -> PRE_U -> HU
    float* B3 = B2 + NH;       // PRE_R -> HR
    int* cnt   = (int*)(B3 + NH);    // [NTOT]
    int* base  = cnt + NTOT;         // [NTOT]
    int* bcnt  = base + NTOT;        // [NBKT]
    int* bbase = bcnt + NBKT;        // [NBKT+1]
    int* bcur  = bbase + NBKT + 1;   // [NBKT]
    int* adj   = bcur + NBKT;        // [2*EE]
    float* wts = (float*)(adj + 2 * EE);
    float* uwT = wts;                // 58*64
    float* rwT = uwT + UF * Hc;      // 128*64
    float* cT[8];
    cT[0] = rwT + RF * Hc;
    for (int i = 1; i < 8; ++i) cT[i] = cT[i - 1] + Hc * Hc;
    __half* TAh = (__half*)(cT[7] + Hc * Hc);  // fp16 T (group-major), user rows
    __half* TBh = TAh + NH;                    // fp16 T (group-major), recipe rows
    int* rec = (int*)B2;             // 16MB alias, dead before first B2 write

    // ---- weight transposes (once) ----
    TP10 tp;
    tp.m[0] = {u_w, uwT, UF};
    tp.m[1] = {r_w, rwT, RF};
    const float* srcs[8] = {c1ra_wl, c1ra_wr, c1rv_wl, c1rv_wr,
                            c2ra_wl, c2ra_wr, c2rv_wl, c2rv_wr};
    for (int i = 0; i < 8; ++i) tp.m[2 + i] = {srcs[i], cT[i], Hc};
    transpose_kernel<<<10, 256, 0, stream>>>(tp);

    // ---- CSR build via bucketed counting sort ----
    hipMemsetAsync(bcnt, 0, (size_t)NBKT * sizeof(int), stream);
    bucket_count_kernel<<<NCHUNK, 256, 0, stream>>>(edge_index, bcnt);
    bucket_scan_kernel<<<1, 256, 0, stream>>>(bcnt, bbase, bcur);
    scatter_records_kernel<<<NCHUNK, 256, 0, stream>>>(edge_index, bcur, rec);
    build_adj_kernel<<<NBKT, 256, 0, stream>>>(rec, bbase, adj, base, cnt);

    // ---- encoders: XU -> B0, XR -> B1 ----
    encode_kernel<UF><<<2048, 256, 0, stream>>>(x_user, uwT, u_b, u_emb, user_nid, B0, NU);
    encode_kernel<RF><<<2048, 256, 0, stream>>>(x_recipe, rwT, r_b, r_emb, rec_nid, B1, NR);

    const int GX = 8 * ((NU + 3) / 4);   // 8 groups x 37500 chunks = 300000 blocks
    // ---- layer 1 dense pair ----
    // U: TU1 = XU@c1ra_wl (TAh); PRE_U = XU@c1rv_wr + c1rv_bl (B2)
    // R: TR1 = XR@c1rv_wl (TBh); PRE_R = XR@c1ra_wr + c1ra_bl (B3)
    dense2_pair_kernel<<<2048, 256, 0, stream>>>(
        B0, cT[0], TAh, cT[3], c1rv_bl, B2,
        B1, cT[2], TBh, cT[1], c1ra_bl, B3);

    // ---- layer 1 gathers (XCD-pinned): HR = relu(PRE_R + mean TU1); HU = relu(PRE_U + mean TR1)
    gather_xcd_kernel<<<GX, 256, 0, stream>>>(TAh, B3, base, cnt, adj, 0, 1);
    gather_xcd_kernel<<<GX, 256, 0, stream>>>(TBh, B2, base, cnt, adj, NR, 1);

    // ---- layer 2 dense pair ----
    // U: TU2 = HU@c2ra_wl (TAh); PRE_U2 = HU@c2rv_wr + c2rv_bl (B0)
    // R: TR2 = HR@c2rv_wl (TBh); PRE_R2 = HR@c2ra_wr + c2ra_bl (B1)
    dense2_pair_kernel<<<2048, 256, 0, stream>>>(
        B2, cT[4], TAh, cT[7], c2rv_bl, B0,
        B3, cT[6], TBh, cT[5], c2ra_bl, B1);

    // ---- layer 2 gathers: HR2 = PRE_R2 + mean TU2 (B1); HU2 = PRE_U2 + mean TR2 (B0)
    gather_xcd_kernel<<<GX, 256, 0, stream>>>(TAh, B1, base, cnt, adj, 0, 0);
    gather_xcd_kernel<<<GX, 256, 0, stream>>>(TBh, B0, base, cnt, adj, NR, 0);

    // ---- classifier: eli[0]=user -> HU2(B0), eli[1]=recipe -> HR2(B1) ----
    edge_dot_kernel<<<(ELc * 16) / 256, 256, 0, stream>>>(edge_label, B0, B1, (float*)d_out);
}

// Round 10
// 786.742 us; speedup vs baseline: 2.3635x; 2.3635x over previous
//
#include <hip/hip_runtime.h>
#include <hip/hip_fp16.h>

constexpr int NU = 150000;
constexpr int NR = 150000;
constexpr int Hc = 64;
constexpr int UF = 58;
constexpr int RF = 128;
constexpr long EE = 2000000;
constexpr long ELc = 500000;
constexpr int NTOT = NU + NR;            // combined ids: [0,NR)=recipes, [NR,NTOT)=users
constexpr int BKT = 256;                 // nodes per bucket
constexpr int NB_R = (NR + BKT - 1) / BKT;   // 586
constexpr int NB_U = (NU + BKT - 1) / BKT;   // 586
constexpr int NBKT = NB_R + NB_U;            // 1172
constexpr int CHUNK = 4096;
constexpr int NCHUNK = (int)((EE + CHUNK - 1) / CHUNK);  // 489
constexpr int GBS = (NU + 3) / 4;        // gather blocks per side (4 rows/block) = 37500

__device__ inline float rdlane(float v, int l) {
    return __uint_as_float(__builtin_amdgcn_readlane(__float_as_uint(v), l));
}

// ---- weight pre-transpose: d[k*64+o] = s[o*F+k] (10 small matrices) ----
struct TP { const float* s; float* d; int F; };
struct TP10 { TP m[10]; };
__global__ void transpose_kernel(TP10 p) {
    TP t = p.m[blockIdx.x];
    for (int idx = threadIdx.x; idx < t.F * Hc; idx += blockDim.x) {
        int k = idx >> 6, o = idx & 63;
        t.d[idx] = t.s[o * t.F + k];
    }
}

// ---- CSR build, pass 0: per-bucket edge counts (LDS-binned) ----
__global__ void bucket_count_kernel(const int* __restrict__ ei, int* __restrict__ bcnt) {
    __shared__ int lc[NBKT];
    for (int i = threadIdx.x; i < NBKT; i += 256) lc[i] = 0;
    __syncthreads();
    long e0 = (long)blockIdx.x * CHUNK;
    for (int k = threadIdx.x; k < CHUNK; k += 256) {
        long e = e0 + k;
        if (e < EE) {
            int u = ei[e], r = ei[EE + e];
            atomicAdd(&lc[r >> 8], 1);
            atomicAdd(&lc[NB_R + (u >> 8)], 1);
        }
    }
    __syncthreads();
    for (int i = threadIdx.x; i < NBKT; i += 256)
        if (lc[i]) atomicAdd(&bcnt[i], lc[i]);
}

// ---- pass 1: exclusive scan over NBKT bucket counts (single block) ----
__global__ void bucket_scan_kernel(const int* __restrict__ bcnt, int* __restrict__ bbase,
                                   int* __restrict__ bcur) {
    __shared__ int part[256];
    constexpr int PER = (NBKT + 255) / 256;   // 5
    int t = threadIdx.x;
    int loc[PER];
    int sum = 0;
    for (int j = 0; j < PER; ++j) {
        int i = t * PER + j;
        int v = (i < NBKT) ? bcnt[i] : 0;
        loc[j] = sum;
        sum += v;
    }
    part[t] = sum;
    __syncthreads();
    for (int off = 1; off < 256; off <<= 1) {
        int v = (t >= off) ? part[t - off] : 0;
        __syncthreads();
        part[t] += v;
        __syncthreads();
    }
    int pre = (t == 0) ? 0 : part[t - 1];
    for (int j = 0; j < PER; ++j) {
        int i = t * PER + j;
        if (i < NBKT) {
            int b = pre + loc[j];
            bbase[i] = b;
            bcur[i] = b;
        }
    }
    if (t == 255) bbase[NBKT] = part[255];
}

// ---- pass 2: chunked-reservation record scatter (4B records: local8|src18) ----
__global__ void scatter_records_kernel(const int* __restrict__ ei, int* __restrict__ bcur,
                                       int* __restrict__ rec) {
    __shared__ int lc[NBKT];
    for (int i = threadIdx.x; i < NBKT; i += 256) lc[i] = 0;
    __syncthreads();
    long e0 = (long)blockIdx.x * CHUNK;
    for (int k = threadIdx.x; k < CHUNK; k += 256) {
        long e = e0 + k;
        if (e < EE) {
            int u = ei[e], r = ei[EE + e];
            atomicAdd(&lc[r >> 8], 1);
            atomicAdd(&lc[NB_R + (u >> 8)], 1);
        }
    }
    __syncthreads();
    for (int i = threadIdx.x; i < NBKT; i += 256) {
        int c = lc[i];
        lc[i] = c ? atomicAdd(&bcur[i], c) : 0;   // reserve contiguous range
    }
    __syncthreads();
    for (int k = threadIdx.x; k < CHUNK; k += 256) {
        long e = e0 + k;
        if (e < EE) {
            int u = ei[e], r = ei[EE + e];
            int p1 = atomicAdd(&lc[r >> 8], 1);
            rec[p1] = ((r & 255) << 18) | u;
            int p2 = atomicAdd(&lc[NB_R + (u >> 8)], 1);
            rec[p2] = ((u & 255) << 18) | r;
        }
    }
}

// ---- pass 3: per-bucket counting sort -> adj (+ per-node base/cnt) ----
__global__ void build_adj_kernel(const int* __restrict__ rec, const int* __restrict__ bbase,
                                 int* __restrict__ adj, int* __restrict__ base,
                                 int* __restrict__ cnt) {
    __shared__ int c256[BKT];
    __shared__ int off256[BKT];
    int b = blockIdx.x;
    int s = bbase[b], e = bbase[b + 1];
    int t = threadIdx.x;
    c256[t] = 0;
    __syncthreads();
    for (int k = s + t; k < e; k += 256) atomicAdd(&c256[rec[k] >> 18], 1);
    __syncthreads();
    int v = c256[t];
    off256[t] = v;
    __syncthreads();
    for (int off = 1; off < 256; off <<= 1) {
        int x = (t >= off) ? off256[t - off] : 0;
        __syncthreads();
        off256[t] += x;
        __syncthreads();
    }
    int excl = off256[t] - v;
    bool isU = (b >= NB_R);
    int node = (isU ? (b - NB_R) : b) * BKT + t;
    int lim = isU ? NU : NR;
    if (node < lim) {
        int cid = isU ? (NR + node) : node;
        base[cid] = s + excl;
        cnt[cid] = v;
    }
    c256[t] = s + excl;    // cursors
    __syncthreads();
    for (int k = s + t; k < e; k += 256) {
        int rv = rec[k];
        int p = atomicAdd(&c256[rv >> 18], 1);
        adj[p] = rv & 0x3FFFF;
    }
}

// ---- node encoder: LDS weights, readlane broadcast, 2-row ILP, fp16 out ----
template <int F>
__global__ __launch_bounds__(256) void encode_kernel(
        const float* __restrict__ xin, const float* __restrict__ wT,
        const float* __restrict__ b, const float* __restrict__ emb,
        const int* __restrict__ nid, __half* __restrict__ out, int N) {
    __shared__ float w[F * Hc];
    for (int idx = threadIdx.x; idx < F * Hc; idx += 256) w[idx] = wT[idx];
    __syncthreads();
    int t = threadIdx.x & 63;
    int wave = (int)((blockIdx.x * blockDim.x + threadIdx.x) >> 6);
    int nwaves = (gridDim.x * blockDim.x) >> 6;
    float bv = b[t];
    for (int r0 = wave * 2; r0 < N; r0 += nwaves * 2) {   // N even -> r0+1 valid
        int rA = r0, rB = r0 + 1;
        float xa0 = (t < F) ? xin[(long)rA * F + t] : 0.0f;
        float xa1 = (F > 64) ? xin[(long)rA * F + 64 + t] : 0.0f;
        float xb0 = (t < F) ? xin[(long)rB * F + t] : 0.0f;
        float xb1 = (F > 64) ? xin[(long)rB * F + 64 + t] : 0.0f;
        float aA0 = bv, aA1 = 0.0f, aB0 = bv, aB1 = 0.0f;
#pragma unroll
        for (int k = 0; k < F; ++k) {
            float wv = w[k * Hc + t];
            float sa = (k < 64) ? rdlane(xa0, k) : rdlane(xa1, k - 64);
            float sb = (k < 64) ? rdlane(xb0, k) : rdlane(xb1, k - 64);
            if (k & 1) { aA1 = fmaf(sa, wv, aA1); aB1 = fmaf(sb, wv, aB1); }
            else       { aA0 = fmaf(sa, wv, aA0); aB0 = fmaf(sb, wv, aB0); }
        }
        float accA = aA0 + aA1 + emb[(long)nid[rA] * Hc + t];
        float accB = aB0 + aB1 + emb[(long)nid[rB] * Hc + t];
        out[(long)rA * Hc + t] = __float2half(accA);
        out[(long)rB * Hc + t] = __float2half(accB);
    }
}

// ---- dense pair (both relations, one dispatch), fp16 in/out, 2-row ILP:
//      T = in@wl^T; PRE = in@wr^T + br. LDS w reads shared across the 2 rows. ----
__global__ __launch_bounds__(256) void dense2_pair_kernel(
        const __half* inU, const float* wlTU, __half* ToutU,
        const float* wrTU, const float* brU, __half* PREU,
        const __half* inR, const float* wlTR, __half* ToutR,
        const float* wrTR, const float* brR, __half* PRER) {
    __shared__ float w[Hc * 128];   // [k][0..63]=wl, [k][64..127]=wr
    int half = gridDim.x >> 1;
    bool isR = blockIdx.x >= half;
    const __half* in  = isR ? inR : inU;
    const float* wlT = isR ? wlTR : wlTU;
    const float* wrT = isR ? wrTR : wrTU;
    const float* br  = isR ? brR : brU;
    __half* Tout = isR ? ToutR : ToutU;
    __half* PRE  = isR ? PRER : PREU;
    for (int idx = threadIdx.x; idx < Hc * Hc; idx += 256) {
        int k = idx >> 6, o = idx & 63;
        w[k * 128 + o] = wlT[idx];
        w[k * 128 + 64 + o] = wrT[idx];
    }
    __syncthreads();
    int t = threadIdx.x & 63;
    int wid = (int)((((long)blockIdx.x - (isR ? half : 0)) * 256 + threadIdx.x) >> 6);
    int nw = (half * 256) >> 6;
    float bv = br[t];
    for (int r0 = wid * 2; r0 < NU; r0 += nw * 2) {   // NU even
        float xva = __half2float(in[(long)r0 * Hc + t]);
        float xvb = __half2float(in[(long)(r0 + 1) * Hc + t]);
        float aAa = 0.0f, aBa = bv, aAb = 0.0f, aBb = bv;
#pragma unroll
        for (int k = 0; k < Hc; ++k) {
            float wl_ = w[k * 128 + t];
            float wr_ = w[k * 128 + 64 + t];
            float sa = rdlane(xva, k);
            float sb = rdlane(xvb, k);
            aAa = fmaf(sa, wl_, aAa); aAb = fmaf(sb, wl_, aAb);
            aBa = fmaf(sa, wr_, aBa); aBb = fmaf(sb, wr_, aBb);
        }
        Tout[(long)r0 * Hc + t] = __float2half(aAa);
        Tout[(long)(r0 + 1) * Hc + t] = __float2half(aAb);
        PRE[(long)r0 * Hc + t] = __float2half(aBa);
        PRE[(long)(r0 + 1) * Hc + t] = __float2half(aBb);
    }
}

// ---- gather pair: io[r] = maybe_relu(io[r] + mean of fp16 T rows), io fp16.
//      Half-waves: lanes [0,32) even neighbors, [32,64) odd; each lane
//      loads a __half2 channel-pair -> one load instr fetches 2 rows. ----
__global__ __launch_bounds__(256) void gather_pair_kernel(
        const __half* __restrict__ TA, __half* __restrict__ ioA,
        const __half* __restrict__ TB, __half* __restrict__ ioB,
        const int* __restrict__ base, const int* __restrict__ cnt,
        const int* __restrict__ adj, int relu) {
    int l = threadIdx.x & 63;
    int g = l >> 5;        // neighbor parity handled by this half-wave
    int c2 = l & 31;       // channel pair: channels (2*c2, 2*c2+1)
    bool isU = blockIdx.x >= GBS;
    int bid = blockIdx.x - (isU ? GBS : 0);
    int r = (int)(((long)bid * 256 + threadIdx.x) >> 6);
    int noff = isU ? NR : 0;
    const __half* T = isU ? TB : TA;
    __half* io = isU ? ioB : ioA;
    int b0 = base[noff + r], c = cnt[noff + r];
    float ax0 = 0.0f, ay0 = 0.0f, ax1 = 0.0f, ay1 = 0.0f;
    int j = 0;
    for (; j + 8 <= c; j += 8) {
        int n0 = adj[b0 + j + g];
        int n1 = adj[b0 + j + 2 + g];
        int n2 = adj[b0 + j + 4 + g];
        int n3 = adj[b0 + j + 6 + g];
        float2 f0 = __half22float2(*(const __half2*)(T + (long)n0 * Hc + 2 * c2));
        float2 f1 = __half22float2(*(const __half2*)(T + (long)n1 * Hc + 2 * c2));
        float2 f2 = __half22float2(*(const __half2*)(T + (long)n2 * Hc + 2 * c2));
        float2 f3 = __half22float2(*(const __half2*)(T + (long)n3 * Hc + 2 * c2));
        ax0 += f0.x + f2.x; ay0 += f0.y + f2.y;
        ax1 += f1.x + f3.x; ay1 += f1.y + f3.y;
    }
    for (; j + 2 <= c; j += 2) {
        int n = adj[b0 + j + g];
        float2 f = __half22float2(*(const __half2*)(T + (long)n * Hc + 2 * c2));
        ax0 += f.x; ay0 += f.y;
    }
    if (j < c && g == 0) {   // odd tail: only even half contributes
        int n = adj[b0 + j];
        float2 f = __half22float2(*(const __half2*)(T + (long)n * Hc + 2 * c2));
        ax0 += f.x; ay0 += f.y;
    }
    float sx = ax0 + ax1, sy = ay0 + ay1;
    sx += __shfl_xor(sx, 32);
    sy += __shfl_xor(sy, 32);
    if (g == 0) {
        float inv = 1.0f / fmaxf((float)c, 1.0f);
        __half2* o = (__half2*)(io + (long)r * Hc + 2 * c2);
        float2 cur = __half22float2(*o);
        float ox = cur.x + sx * inv;
        float oy = cur.y + sy * inv;
        if (relu) { ox = fmaxf(ox, 0.0f); oy = fmaxf(oy, 0.0f); }
        *o = __floats2half2_rn(ox, oy);
    }
}

// ---- edge dot-product classifier (fp16 H inputs, f32 out) ----
__global__ void edge_dot_kernel(const int* __restrict__ eli,
                                const __half* __restrict__ HU2, const __half* __restrict__ HR2,
                                float* __restrict__ out) {
    long gid = (long)blockIdx.x * blockDim.x + threadIdx.x;
    long e = gid >> 4;
    int t = (int)(gid & 15);
    if (e >= ELc) return;
    int a = eli[e], b = eli[ELc + e];
    const __half2* xa = (const __half2*)(HU2 + (long)a * Hc + t * 4);
    const __half2* yb = (const __half2*)(HR2 + (long)b * Hc + t * 4);
    float2 x0 = __half22float2(xa[0]), x1 = __half22float2(xa[1]);
    float2 y0 = __half22float2(yb[0]), y1 = __half22float2(yb[1]);
    float v = x0.x * y0.x + x0.y * y0.y + x1.x * y1.x + x1.y * y1.y;
    v += __shfl_xor(v, 1);
    v += __shfl_xor(v, 2);
    v += __shfl_xor(v, 4);
    v += __shfl_xor(v, 8);
    if (t == 0) out[e] = v;
}

extern "C" void kernel_launch(void* const* d_in, const int* in_sizes, int n_in,
                              void* d_out, int out_size, void* d_ws, size_t ws_size,
                              hipStream_t stream) {
    const float* x_user   = (const float*)d_in[0];
    const float* x_recipe = (const float*)d_in[1];
    const int*   user_nid = (const int*)d_in[2];
    const int*   rec_nid  = (const int*)d_in[3];
    const int*   edge_index = (const int*)d_in[4];
    const int*   edge_label = (const int*)d_in[5];
    const float* u_w   = (const float*)d_in[6];
    const float* u_b   = (const float*)d_in[7];
    const float* r_w   = (const float*)d_in[8];
    const float* r_b   = (const float*)d_in[9];
    const float* u_emb = (const float*)d_in[10];
    const float* r_emb = (const float*)d_in[11];
    const float* c1ra_wl = (const float*)d_in[12];
    const float* c1ra_bl = (const float*)d_in[13];
    const float* c1ra_wr = (const float*)d_in[14];
    const float* c1rv_wl = (const float*)d_in[15];
    const float* c1rv_bl = (const float*)d_in[16];
    const float* c1rv_wr = (const float*)d_in[17];
    const float* c2ra_wl = (const float*)d_in[18];
    const float* c2ra_bl = (const float*)d_in[19];
    const float* c2ra_wr = (const float*)d_in[20];
    const float* c2rv_wl = (const float*)d_in[21];
    const float* c2rv_bl = (const float*)d_in[22];
    const float* c2rv_wr = (const float*)d_in[23];

    const long NH = (long)NU * Hc;
    __half* B0 = (__half*)d_ws;      // XU -> PRE_U2 -> HU2
    __half* B1 = B0 + NH;            // XR -> PRE_R2 -> HR2
    __half* B2 = B1 + NH;            // rec alias -> PRE_U -> HU
    __half* B3 = B2 + NH;            // PRE_R -> HR
    __half* TAh = B3 + NH;           // fp16 T, user rows
    __half* TBh = TAh + NH;          // fp16 T, recipe rows
    int* cnt   = (int*)(TBh + NH);   // [NTOT]
    int* base  = cnt + NTOT;         // [NTOT]
    int* bcnt  = base + NTOT;        // [NBKT]
    int* bbase = bcnt + NBKT;        // [NBKT+1]
    int* bcur  = bbase + NBKT + 1;   // [NBKT]
    int* adj   = bcur + NBKT;        // [2*EE]
    float* wts = (float*)(adj + 2 * EE);
    float* uwT = wts;                // 58*64
    float* rwT = uwT + UF * Hc;      // 128*64
    float* cT[8];
    cT[0] = rwT + RF * Hc;
    for (int i = 1; i < 8; ++i) cT[i] = cT[i - 1] + Hc * Hc;
    int* rec = (int*)B2;             // 16MB alias (B2 is 19.2MB), dead before first B2 write

    // ---- weight transposes (once) ----
    TP10 tp;
    tp.m[0] = {u_w, uwT, UF};
    tp.m[1] = {r_w, rwT, RF};
    const float* srcs[8] = {c1ra_wl, c1ra_wr, c1rv_wl, c1rv_wr,
                            c2ra_wl, c2ra_wr, c2rv_wl, c2rv_wr};
    for (int i = 0; i < 8; ++i) tp.m[2 + i] = {srcs[i], cT[i], Hc};
    transpose_kernel<<<10, 256, 0, stream>>>(tp);

    // ---- CSR build via bucketed counting sort ----
    hipMemsetAsync(bcnt, 0, (size_t)NBKT * sizeof(int), stream);
    bucket_count_kernel<<<NCHUNK, 256, 0, stream>>>(edge_index, bcnt);
    bucket_scan_kernel<<<1, 256, 0, stream>>>(bcnt, bbase, bcur);
    scatter_records_kernel<<<NCHUNK, 256, 0, stream>>>(edge_index, bcur, rec);
    build_adj_kernel<<<NBKT, 256, 0, stream>>>(rec, bbase, adj, base, cnt);

    // ---- encoders: XU -> B0, XR -> B1 (fp16) ----
    encode_kernel<UF><<<2048, 256, 0, stream>>>(x_user, uwT, u_b, u_emb, user_nid, B0, NU);
    encode_kernel<RF><<<2048, 256, 0, stream>>>(x_recipe, rwT, r_b, r_emb, rec_nid, B1, NR);

    // ---- layer 1 dense pair ----
    // U: TU1 = XU@c1ra_wl (TAh); PRE_U = XU@c1rv_wr + c1rv_bl (B2)
    // R: TR1 = XR@c1rv_wl (TBh); PRE_R = XR@c1ra_wr + c1ra_bl (B3)
    dense2_pair_kernel<<<2048, 256, 0, stream>>>(
        B0, cT[0], TAh, cT[3], c1rv_bl, B2,
        B1, cT[2], TBh, cT[1], c1ra_bl, B3);

    // ---- layer 1 gathers: HR = relu(PRE_R + mean TU1) (B3); HU = relu(PRE_U + mean TR1) (B2)
    gather_pair_kernel<<<2 * GBS, 256, 0, stream>>>(TAh, B3, TBh, B2, base, cnt, adj, 1);

    // ---- layer 2 dense pair ----
    // U: TU2 = HU@c2ra_wl (TAh); PRE_U2 = HU@c2rv_wr + c2rv_bl (B0)
    // R: TR2 = HR@c2rv_wl (TBh); PRE_R2 = HR@c2ra_wr + c2ra_bl (B1)
    dense2_pair_kernel<<<2048, 256, 0, stream>>>(
        B2, cT[4], TAh, cT[7], c2rv_bl, B0,
        B3, cT[6], TBh, cT[5], c2ra_bl, B1);

    // ---- layer 2 gathers: HR2 = PRE_R2 + mean TU2 (B1); HU2 = PRE_U2 + mean TR2 (B0)
    gather_pair_kernel<<<2 * GBS, 256, 0, stream>>>(TAh, B1, TBh, B0, base, cnt, adj, 0);

    // ---- classifier: eli[0]=user -> HU2(B0), eli[1]=recipe -> HR2(B1) ----
    edge_dot_kernel<<<(ELc * 16) / 256, 256, 0, stream>>>(edge_label, B0, B1, (float*)d_out);
}

// Round 11
// 687.798 us; speedup vs baseline: 2.7035x; 1.1439x over previous
//
#include <hip/hip_runtime.h>
#include <hip/hip_fp16.h>

constexpr int NU = 150000;
constexpr int NR = 150000;
constexpr int Hc = 64;
constexpr int UF = 58;
constexpr int RF = 128;
constexpr long EE = 2000000;
constexpr long ELc = 500000;
constexpr int NTOT = NU + NR;            // combined ids: [0,NR)=recipes, [NR,NTOT)=users
constexpr int BKT = 256;
constexpr int NB_R = (NR + BKT - 1) / BKT;   // 586
constexpr int NB_U = (NU + BKT - 1) / BKT;   // 586
constexpr int NBKT = NB_R + NB_U;            // 1172
constexpr int CHUNK = 4096;
constexpr int NCHUNK = (int)((EE + CHUNK - 1) / CHUNK);  // 489
constexpr int GBS = (NU + 3) / 4;        // gather blocks per side = 37500
constexpr int NTILE = NU / 16;           // 9375 row-tiles (exact)

typedef _Float16 f16;
typedef f16 f16x8 __attribute__((ext_vector_type(8)));
typedef float f32x4 __attribute__((ext_vector_type(4)));

// ---- CSR build, pass 0: per-bucket edge counts (LDS-binned) ----
__global__ void bucket_count_kernel(const int* __restrict__ ei, int* __restrict__ bcnt) {
    __shared__ int lc[NBKT];
    for (int i = threadIdx.x; i < NBKT; i += 256) lc[i] = 0;
    __syncthreads();
    long e0 = (long)blockIdx.x * CHUNK;
    for (int k = threadIdx.x; k < CHUNK; k += 256) {
        long e = e0 + k;
        if (e < EE) {
            int u = ei[e], r = ei[EE + e];
            atomicAdd(&lc[r >> 8], 1);
            atomicAdd(&lc[NB_R + (u >> 8)], 1);
        }
    }
    __syncthreads();
    for (int i = threadIdx.x; i < NBKT; i += 256)
        if (lc[i]) atomicAdd(&bcnt[i], lc[i]);
}

// ---- pass 1: exclusive scan over NBKT bucket counts (single block) ----
__global__ void bucket_scan_kernel(const int* __restrict__ bcnt, int* __restrict__ bbase,
                                   int* __restrict__ bcur) {
    __shared__ int part[256];
    constexpr int PER = (NBKT + 255) / 256;   // 5
    int t = threadIdx.x;
    int loc[PER];
    int sum = 0;
    for (int j = 0; j < PER; ++j) {
        int i = t * PER + j;
        int v = (i < NBKT) ? bcnt[i] : 0;
        loc[j] = sum;
        sum += v;
    }
    part[t] = sum;
    __syncthreads();
    for (int off = 1; off < 256; off <<= 1) {
        int v = (t >= off) ? part[t - off] : 0;
        __syncthreads();
        part[t] += v;
        __syncthreads();
    }
    int pre = (t == 0) ? 0 : part[t - 1];
    for (int j = 0; j < PER; ++j) {
        int i = t * PER + j;
        if (i < NBKT) {
            int b = pre + loc[j];
            bbase[i] = b;
            bcur[i] = b;
        }
    }
    if (t == 255) bbase[NBKT] = part[255];
}

// ---- pass 2: chunked-reservation record scatter (4B records: local8|src18) ----
__global__ void scatter_records_kernel(const int* __restrict__ ei, int* __restrict__ bcur,
                                       int* __restrict__ rec) {
    __shared__ int lc[NBKT];
    for (int i = threadIdx.x; i < NBKT; i += 256) lc[i] = 0;
    __syncthreads();
    long e0 = (long)blockIdx.x * CHUNK;
    for (int k = threadIdx.x; k < CHUNK; k += 256) {
        long e = e0 + k;
        if (e < EE) {
            int u = ei[e], r = ei[EE + e];
            atomicAdd(&lc[r >> 8], 1);
            atomicAdd(&lc[NB_R + (u >> 8)], 1);
        }
    }
    __syncthreads();
    for (int i = threadIdx.x; i < NBKT; i += 256) {
        int c = lc[i];
        lc[i] = c ? atomicAdd(&bcur[i], c) : 0;   // reserve contiguous range
    }
    __syncthreads();
    for (int k = threadIdx.x; k < CHUNK; k += 256) {
        long e = e0 + k;
        if (e < EE) {
            int u = ei[e], r = ei[EE + e];
            int p1 = atomicAdd(&lc[r >> 8], 1);
            rec[p1] = ((r & 255) << 18) | u;
            int p2 = atomicAdd(&lc[NB_R + (u >> 8)], 1);
            rec[p2] = ((u & 255) << 18) | r;
        }
    }
}

// ---- pass 3: per-bucket counting sort -> adj (+ per-node base/cnt) ----
__global__ void build_adj_kernel(const int* __restrict__ rec, const int* __restrict__ bbase,
                                 int* __restrict__ adj, int* __restrict__ base,
                                 int* __restrict__ cnt) {
    __shared__ int c256[BKT];
    __shared__ int off256[BKT];
    int b = blockIdx.x;
    int s = bbase[b], e = bbase[b + 1];
    int t = threadIdx.x;
    c256[t] = 0;
    __syncthreads();
    for (int k = s + t; k < e; k += 256) atomicAdd(&c256[rec[k] >> 18], 1);
    __syncthreads();
    int v = c256[t];
    off256[t] = v;
    __syncthreads();
    for (int off = 1; off < 256; off <<= 1) {
        int x = (t >= off) ? off256[t - off] : 0;
        __syncthreads();
        off256[t] += x;
        __syncthreads();
    }
    int excl = off256[t] - v;
    bool isU = (b >= NB_R);
    int node = (isU ? (b - NB_R) : b) * BKT + t;
    int lim = isU ? NU : NR;
    if (node < lim) {
        int cid = isU ? (NR + node) : node;
        base[cid] = s + excl;
        cnt[cid] = v;
    }
    c256[t] = s + excl;    // cursors
    __syncthreads();
    for (int k = s + t; k < e; k += 256) {
        int rv = rec[k];
        int p = atomicAdd(&c256[rv >> 18], 1);
        adj[p] = rv & 0x3FFFF;
    }
}

// ---- MFMA node encoder: out(fp16) = x@W^T + b + emb[nid].
//      Wave computes a 16-row x 64-col tile; B-frags read W rows directly. ----
template <int F>
__global__ __launch_bounds__(256) void encode_mfma(
        const float* __restrict__ xin, const float* __restrict__ w,   // w [64][F]
        const float* __restrict__ b, const float* __restrict__ emb,
        const int* __restrict__ nid, __half* __restrict__ out) {
    constexpr int KT = (F + 31) / 32;
    int l = threadIdx.x & 63;
    int m = l & 15;
    int g = l >> 4;
    // B fragments: bf[ct][kt][j] = w[ct*16+m][kt*32+g*8+j]
    f16x8 bf[4][KT];
#pragma unroll
    for (int ct = 0; ct < 4; ++ct)
#pragma unroll
        for (int kt = 0; kt < KT; ++kt)
#pragma unroll
            for (int j = 0; j < 8; ++j) {
                int k = kt * 32 + g * 8 + j;
                bf[ct][kt][j] = (k < F) ? (f16)w[(ct * 16 + m) * F + k] : (f16)0.0f;
            }
    int rt = (int)(((long)blockIdx.x * blockDim.x + threadIdx.x) >> 6);
    if (rt >= NTILE) return;
    int r0 = rt * 16;
    // A fragments: af[kt][j] = x[r0+m][kt*32+g*8+j]
    f16x8 af[KT];
    const float* xrow = xin + (long)(r0 + m) * F;
#pragma unroll
    for (int kt = 0; kt < KT; ++kt)
#pragma unroll
        for (int j = 0; j < 8; ++j) {
            int k = kt * 32 + g * 8 + j;
            af[kt][j] = (k < F) ? (f16)xrow[k] : (f16)0.0f;
        }
    f32x4 acc[4] = {{0,0,0,0},{0,0,0,0},{0,0,0,0},{0,0,0,0}};
#pragma unroll
    for (int ct = 0; ct < 4; ++ct)
#pragma unroll
        for (int kt = 0; kt < KT; ++kt)
            acc[ct] = __builtin_amdgcn_mfma_f32_16x16x32_f16(af[kt], bf[ct][kt], acc[ct], 0, 0, 0);
    // epilogue: D[row=g*4+q][col=ct*16+m]
#pragma unroll
    for (int q = 0; q < 4; ++q) {
        int r = r0 + g * 4 + q;
        long ebase = (long)nid[r] * Hc;
#pragma unroll
        for (int ct = 0; ct < 4; ++ct) {
            int col = ct * 16 + m;
            float v = acc[ct][q] + b[col] + emb[ebase + col];
            out[(long)r * Hc + col] = __float2half(v);
        }
    }
}

// ---- MFMA dense pair (both relations in one dispatch):
//      T = in@wl^T (fp16); PRE = in@wr^T + br (fp16). in fp16 [N][64]. ----
__global__ __launch_bounds__(256) void dense2_mfma(
        const __half* inU, const float* wlU, const float* brU, const float* wrU,
        __half* ToutU, __half* PREU,
        const __half* inR, const float* wlR, const float* brR, const float* wrR,
        __half* ToutR, __half* PRER) {
    int half = gridDim.x >> 1;
    bool isR = blockIdx.x >= half;
    const __half* in = isR ? inR : inU;
    const float* wl = isR ? wlR : wlU;
    const float* wr = isR ? wrR : wrU;
    const float* br = isR ? brR : brU;
    __half* Tout = isR ? ToutR : ToutU;
    __half* PRE  = isR ? PRER : PREU;
    int l = threadIdx.x & 63;
    int m = l & 15;
    int g = l >> 4;
    // B fragments: [0..3]=wl cts, [4..7]=wr cts; kt in 0..1
    f16x8 bf[8][2];
#pragma unroll
    for (int ct = 0; ct < 4; ++ct)
#pragma unroll
        for (int kt = 0; kt < 2; ++kt)
#pragma unroll
            for (int j = 0; j < 8; ++j) {
                int k = kt * 32 + g * 8 + j;
                bf[ct][kt][j]     = (f16)wl[(ct * 16 + m) * Hc + k];
                bf[4 + ct][kt][j] = (f16)wr[(ct * 16 + m) * Hc + k];
            }
    int rt = (int)((((long)blockIdx.x - (isR ? half : 0)) * blockDim.x + threadIdx.x) >> 6);
    if (rt >= NTILE) return;
    int r0 = rt * 16;
    f16x8 af[2];
    const __half* irow = in + (long)(r0 + m) * Hc;
    af[0] = *(const f16x8*)(irow + g * 8);
    af[1] = *(const f16x8*)(irow + 32 + g * 8);
    f32x4 acc[8] = {{0,0,0,0},{0,0,0,0},{0,0,0,0},{0,0,0,0},
                    {0,0,0,0},{0,0,0,0},{0,0,0,0},{0,0,0,0}};
#pragma unroll
    for (int ct = 0; ct < 8; ++ct)
#pragma unroll
        for (int kt = 0; kt < 2; ++kt)
            acc[ct] = __builtin_amdgcn_mfma_f32_16x16x32_f16(af[kt], bf[ct][kt], acc[ct], 0, 0, 0);
#pragma unroll
    for (int q = 0; q < 4; ++q) {
        int r = r0 + g * 4 + q;
#pragma unroll
        for (int ct = 0; ct < 4; ++ct) {
            int col = ct * 16 + m;
            Tout[(long)r * Hc + col] = __float2half(acc[ct][q]);
            PRE[(long)r * Hc + col] = __float2half(acc[4 + ct][q] + br[col]);
        }
    }
}

// ---- gather pair: io[r] = maybe_relu(io[r] + mean of fp16 T rows), io fp16.
//      Half-waves over neighbor parity; per-lane __half2 channel pair;
//      packed fp16 accumulation (v_pk_add_f16). ----
__global__ __launch_bounds__(256) void gather_pair_kernel(
        const __half* __restrict__ TA, __half* __restrict__ ioA,
        const __half* __restrict__ TB, __half* __restrict__ ioB,
        const int* __restrict__ base, const int* __restrict__ cnt,
        const int* __restrict__ adj, int relu) {
    int l = threadIdx.x & 63;
    int g = l >> 5;        // neighbor parity handled by this half-wave
    int c2 = l & 31;       // channel pair: channels (2*c2, 2*c2+1)
    bool isU = blockIdx.x >= GBS;
    int bid = blockIdx.x - (isU ? GBS : 0);
    int r = (int)(((long)bid * 256 + threadIdx.x) >> 6);
    int noff = isU ? NR : 0;
    const __half* T = isU ? TB : TA;
    __half* io = isU ? ioB : ioA;
    int b0 = base[noff + r], c = cnt[noff + r];
    __half2 s0 = __float2half2_rn(0.0f), s1 = s0, s2 = s0, s3 = s0;
    int j = 0;
    for (; j + 8 <= c; j += 8) {
        int n0 = adj[b0 + j + g];
        int n1 = adj[b0 + j + 2 + g];
        int n2 = adj[b0 + j + 4 + g];
        int n3 = adj[b0 + j + 6 + g];
        s0 = __hadd2(s0, *(const __half2*)(T + (long)n0 * Hc + 2 * c2));
        s1 = __hadd2(s1, *(const __half2*)(T + (long)n1 * Hc + 2 * c2));
        s2 = __hadd2(s2, *(const __half2*)(T + (long)n2 * Hc + 2 * c2));
        s3 = __hadd2(s3, *(const __half2*)(T + (long)n3 * Hc + 2 * c2));
    }
    for (; j + 2 <= c; j += 2) {
        int n = adj[b0 + j + g];
        s0 = __hadd2(s0, *(const __half2*)(T + (long)n * Hc + 2 * c2));
    }
    if (j < c && g == 0) {   // odd tail: only even half contributes
        int n = adj[b0 + j];
        s0 = __hadd2(s0, *(const __half2*)(T + (long)n * Hc + 2 * c2));
    }
    float2 f = __half22float2(__hadd2(__hadd2(s0, s1), __hadd2(s2, s3)));
    float sx = f.x, sy = f.y;
    sx += __shfl_xor(sx, 32);
    sy += __shfl_xor(sy, 32);
    if (g == 0) {
        float inv = 1.0f / fmaxf((float)c, 1.0f);
        __half2* o = (__half2*)(io + (long)r * Hc + 2 * c2);
        float2 cur = __half22float2(*o);
        float ox = cur.x + sx * inv;
        float oy = cur.y + sy * inv;
        if (relu) { ox = fmaxf(ox, 0.0f); oy = fmaxf(oy, 0.0f); }
        *o = __floats2half2_rn(ox, oy);
    }
}

// ---- edge dot-product classifier (fp16 H inputs, f32 out) ----
__global__ void edge_dot_kernel(const int* __restrict__ eli,
                                const __half* __restrict__ HU2, const __half* __restrict__ HR2,
                                float* __restrict__ out) {
    long gid = (long)blockIdx.x * blockDim.x + threadIdx.x;
    long e = gid >> 4;
    int t = (int)(gid & 15);
    if (e >= ELc) return;
    int a = eli[e], b = eli[ELc + e];
    const __half2* xa = (const __half2*)(HU2 + (long)a * Hc + t * 4);
    const __half2* yb = (const __half2*)(HR2 + (long)b * Hc + t * 4);
    float2 x0 = __half22float2(xa[0]), x1 = __half22float2(xa[1]);
    float2 y0 = __half22float2(yb[0]), y1 = __half22float2(yb[1]);
    float v = x0.x * y0.x + x0.y * y0.y + x1.x * y1.x + x1.y * y1.y;
    v += __shfl_xor(v, 1);
    v += __shfl_xor(v, 2);
    v += __shfl_xor(v, 4);
    v += __shfl_xor(v, 8);
    if (t == 0) out[e] = v;
}

extern "C" void kernel_launch(void* const* d_in, const int* in_sizes, int n_in,
                              void* d_out, int out_size, void* d_ws, size_t ws_size,
                              hipStream_t stream) {
    const float* x_user   = (const float*)d_in[0];
    const float* x_recipe = (const float*)d_in[1];
    const int*   user_nid = (const int*)d_in[2];
    const int*   rec_nid  = (const int*)d_in[3];
    const int*   edge_index = (const int*)d_in[4];
    const int*   edge_label = (const int*)d_in[5];
    const float* u_w   = (const float*)d_in[6];
    const float* u_b   = (const float*)d_in[7];
    const float* r_w   = (const float*)d_in[8];
    const float* r_b   = (const float*)d_in[9];
    const float* u_emb = (const float*)d_in[10];
    const float* r_emb = (const float*)d_in[11];
    const float* c1ra_wl = (const float*)d_in[12];
    const float* c1ra_bl = (const float*)d_in[13];
    const float* c1ra_wr = (const float*)d_in[14];
    const float* c1rv_wl = (const float*)d_in[15];
    const float* c1rv_bl = (const float*)d_in[16];
    const float* c1rv_wr = (const float*)d_in[17];
    const float* c2ra_wl = (const float*)d_in[18];
    const float* c2ra_bl = (const float*)d_in[19];
    const float* c2ra_wr = (const float*)d_in[20];
    const float* c2rv_wl = (const float*)d_in[21];
    const float* c2rv_bl = (const float*)d_in[22];
    const float* c2rv_wr = (const float*)d_in[23];

    const long NH = (long)NU * Hc;
    __half* B0 = (__half*)d_ws;      // XU -> PRE_U2 -> HU2
    __half* B1 = B0 + NH;            // XR -> PRE_R2 -> HR2
    __half* B2 = B1 + NH;            // rec alias -> PRE_U -> HU
    __half* B3 = B2 + NH;            // PRE_R -> HR
    __half* TAh = B3 + NH;           // fp16 T, user rows
    __half* TBh = TAh + NH;          // fp16 T, recipe rows
    int* cnt   = (int*)(TBh + NH);   // [NTOT]
    int* base  = cnt + NTOT;         // [NTOT]
    int* bcnt  = base + NTOT;        // [NBKT]
    int* bbase = bcnt + NBKT;        // [NBKT+1]
    int* bcur  = bbase + NBKT + 1;   // [NBKT]
    int* adj   = bcur + NBKT;        // [2*EE]
    int* rec = (int*)B2;             // 16MB alias (B2 is 19.2MB), dead before first B2 write

    // ---- CSR build via bucketed counting sort ----
    hipMemsetAsync(bcnt, 0, (size_t)NBKT * sizeof(int), stream);
    bucket_count_kernel<<<NCHUNK, 256, 0, stream>>>(edge_index, bcnt);
    bucket_scan_kernel<<<1, 256, 0, stream>>>(bcnt, bbase, bcur);
    scatter_records_kernel<<<NCHUNK, 256, 0, stream>>>(edge_index, bcur, rec);
    build_adj_kernel<<<NBKT, 256, 0, stream>>>(rec, bbase, adj, base, cnt);

    const int EB = (NTILE + 3) / 4;   // 2344 blocks (4 waves/block)
    // ---- encoders (MFMA): XU -> B0, XR -> B1 (fp16) ----
    encode_mfma<UF><<<EB, 256, 0, stream>>>(x_user, u_w, u_b, u_emb, user_nid, B0);
    encode_mfma<RF><<<EB, 256, 0, stream>>>(x_recipe, r_w, r_b, r_emb, rec_nid, B1);

    // ---- layer 1 dense pair (MFMA) ----
    // U: TU1 = XU@c1ra_wl (TAh); PRE_U = XU@c1rv_wr + c1rv_bl (B2)
    // R: TR1 = XR@c1rv_wl (TBh); PRE_R = XR@c1ra_wr + c1ra_bl (B3)
    dense2_mfma<<<2 * EB, 256, 0, stream>>>(
        B0, c1ra_wl, c1rv_bl, c1rv_wr, TAh, B2,
        B1, c1rv_wl, c1ra_bl, c1ra_wr, TBh, B3);

    // ---- layer 1 gathers: HR = relu(PRE_R + mean TU1) (B3); HU = relu(PRE_U + mean TR1) (B2)
    gather_pair_kernel<<<2 * GBS, 256, 0, stream>>>(TAh, B3, TBh, B2, base, cnt, adj, 1);

    // ---- layer 2 dense pair (MFMA) ----
    // U: TU2 = HU@c2ra_wl (TAh); PRE_U2 = HU@c2rv_wr + c2rv_bl (B0)
    // R: TR2 = HR@c2rv_wl (TBh); PRE_R2 = HR@c2ra_wr + c2ra_bl (B1)
    dense2_mfma<<<2 * EB, 256, 0, stream>>>(
        B2, c2ra_wl, c2rv_bl, c2rv_wr, TAh, B0,
        B3, c2rv_wl, c2ra_bl, c2ra_wr, TBh, B1);

    // ---- layer 2 gathers: HR2 = PRE_R2 + mean TU2 (B1); HU2 = PRE_U2 + mean TR2 (B0)
    gather_pair_kernel<<<2 * GBS, 256, 0, stream>>>(TAh, B1, TBh, B0, base, cnt, adj, 0);

    // ---- classifier: eli[0]=user -> HU2(B0), eli[1]=recipe -> HR2(B1) ----
    edge_dot_kernel<<<(ELc * 16) / 256, 256, 0, stream>>>(edge_label, B0, B1, (float*)d_out);
}

// Round 12
// 634.902 us; speedup vs baseline: 2.9287x; 1.0833x over previous
//
#include <hip/hip_runtime.h>
#include <hip/hip_fp16.h>

constexpr int NU = 150000;
constexpr int NR = 150000;
constexpr int Hc = 64;
constexpr int UF = 58;
constexpr int RF = 128;
constexpr long EE = 2000000;
constexpr long ELc = 500000;
constexpr int NTOT = NU + NR;            // combined ids: [0,NR)=recipes, [NR,NTOT)=users
constexpr int BKT = 256;
constexpr int NB_R = (NR + BKT - 1) / BKT;   // 586
constexpr int NB_U = (NU + BKT - 1) / BKT;   // 586
constexpr int NBKT = NB_R + NB_U;            // 1172
constexpr int CHUNK = 4096;
constexpr int NCHUNK = (int)((EE + CHUNK - 1) / CHUNK);  // 489
constexpr int GBS = (NU + 3) / 4;        // gather blocks per side = 37500
constexpr int NTILE = NU / 16;           // 9375 row-tiles (exact)

typedef _Float16 f16;
typedef f16 f16x8 __attribute__((ext_vector_type(8)));
typedef float f32x4 __attribute__((ext_vector_type(4)));

__device__ inline __half2 shx2(__half2 v, int m) {
    int i = *(int*)&v;
    i = __shfl_xor(i, m);
    return *(__half2*)&i;
}

// ---- CSR build, pass 0: per-bucket edge counts (LDS-binned) ----
__global__ void bucket_count_kernel(const int* __restrict__ ei, int* __restrict__ bcnt) {
    __shared__ int lc[NBKT];
    for (int i = threadIdx.x; i < NBKT; i += 256) lc[i] = 0;
    __syncthreads();
    long e0 = (long)blockIdx.x * CHUNK;
    for (int k = threadIdx.x; k < CHUNK; k += 256) {
        long e = e0 + k;
        if (e < EE) {
            int u = ei[e], r = ei[EE + e];
            atomicAdd(&lc[r >> 8], 1);
            atomicAdd(&lc[NB_R + (u >> 8)], 1);
        }
    }
    __syncthreads();
    for (int i = threadIdx.x; i < NBKT; i += 256)
        if (lc[i]) atomicAdd(&bcnt[i], lc[i]);
}

// ---- pass 1: exclusive scan over NBKT bucket counts (single block) ----
__global__ void bucket_scan_kernel(const int* __restrict__ bcnt, int* __restrict__ bbase,
                                   int* __restrict__ bcur) {
    __shared__ int part[256];
    constexpr int PER = (NBKT + 255) / 256;   // 5
    int t = threadIdx.x;
    int loc[PER];
    int sum = 0;
    for (int j = 0; j < PER; ++j) {
        int i = t * PER + j;
        int v = (i < NBKT) ? bcnt[i] : 0;
        loc[j] = sum;
        sum += v;
    }
    part[t] = sum;
    __syncthreads();
    for (int off = 1; off < 256; off <<= 1) {
        int v = (t >= off) ? part[t - off] : 0;
        __syncthreads();
        part[t] += v;
        __syncthreads();
    }
    int pre = (t == 0) ? 0 : part[t - 1];
    for (int j = 0; j < PER; ++j) {
        int i = t * PER + j;
        if (i < NBKT) {
            int b = pre + loc[j];
            bbase[i] = b;
            bcur[i] = b;
        }
    }
    if (t == 255) bbase[NBKT] = part[255];
}

// ---- pass 2: chunked-reservation record scatter (4B records: local8|src18) ----
__global__ void scatter_records_kernel(const int* __restrict__ ei, int* __restrict__ bcur,
                                       int* __restrict__ rec) {
    __shared__ int lc[NBKT];
    for (int i = threadIdx.x; i < NBKT; i += 256) lc[i] = 0;
    __syncthreads();
    long e0 = (long)blockIdx.x * CHUNK;
    for (int k = threadIdx.x; k < CHUNK; k += 256) {
        long e = e0 + k;
        if (e < EE) {
            int u = ei[e], r = ei[EE + e];
            atomicAdd(&lc[r >> 8], 1);
            atomicAdd(&lc[NB_R + (u >> 8)], 1);
        }
    }
    __syncthreads();
    for (int i = threadIdx.x; i < NBKT; i += 256) {
        int c = lc[i];
        lc[i] = c ? atomicAdd(&bcur[i], c) : 0;   // reserve contiguous range
    }
    __syncthreads();
    for (int k = threadIdx.x; k < CHUNK; k += 256) {
        long e = e0 + k;
        if (e < EE) {
            int u = ei[e], r = ei[EE + e];
            int p1 = atomicAdd(&lc[r >> 8], 1);
            rec[p1] = ((r & 255) << 18) | u;
            int p2 = atomicAdd(&lc[NB_R + (u >> 8)], 1);
            rec[p2] = ((u & 255) << 18) | r;
        }
    }
}

// ---- pass 3: per-bucket counting sort -> adj (+ per-node base/cnt) ----
__global__ void build_adj_kernel(const int* __restrict__ rec, const int* __restrict__ bbase,
                                 int* __restrict__ adj, int* __restrict__ base,
                                 int* __restrict__ cnt) {
    __shared__ int c256[BKT];
    __shared__ int off256[BKT];
    int b = blockIdx.x;
    int s = bbase[b], e = bbase[b + 1];
    int t = threadIdx.x;
    c256[t] = 0;
    __syncthreads();
    for (int k = s + t; k < e; k += 256) atomicAdd(&c256[rec[k] >> 18], 1);
    __syncthreads();
    int v = c256[t];
    off256[t] = v;
    __syncthreads();
    for (int off = 1; off < 256; off <<= 1) {
        int x = (t >= off) ? off256[t - off] : 0;
        __syncthreads();
        off256[t] += x;
        __syncthreads();
    }
    int excl = off256[t] - v;
    bool isU = (b >= NB_R);
    int node = (isU ? (b - NB_R) : b) * BKT + t;
    int lim = isU ? NU : NR;
    if (node < lim) {
        int cid = isU ? (NR + node) : node;
        base[cid] = s + excl;
        cnt[cid] = v;
    }
    c256[t] = s + excl;    // cursors
    __syncthreads();
    for (int k = s + t; k < e; k += 256) {
        int rv = rec[k];
        int p = atomicAdd(&c256[rv >> 18], 1);
        adj[p] = rv & 0x3FFFF;
    }
}

// ---- MFMA node encoder: out(fp16) = x@W^T + b + emb[nid]. ----
template <int F>
__global__ __launch_bounds__(256) void encode_mfma(
        const float* __restrict__ xin, const float* __restrict__ w,   // w [64][F]
        const float* __restrict__ b, const float* __restrict__ emb,
        const int* __restrict__ nid, __half* __restrict__ out) {
    constexpr int KT = (F + 31) / 32;
    int l = threadIdx.x & 63;
    int m = l & 15;
    int g = l >> 4;
    f16x8 bf[4][KT];
#pragma unroll
    for (int ct = 0; ct < 4; ++ct)
#pragma unroll
        for (int kt = 0; kt < KT; ++kt)
#pragma unroll
            for (int j = 0; j < 8; ++j) {
                int k = kt * 32 + g * 8 + j;
                bf[ct][kt][j] = (k < F) ? (f16)w[(ct * 16 + m) * F + k] : (f16)0.0f;
            }
    int rt = (int)(((long)blockIdx.x * blockDim.x + threadIdx.x) >> 6);
    if (rt >= NTILE) return;
    int r0 = rt * 16;
    f16x8 af[KT];
    const float* xrow = xin + (long)(r0 + m) * F;
#pragma unroll
    for (int kt = 0; kt < KT; ++kt)
#pragma unroll
        for (int j = 0; j < 8; ++j) {
            int k = kt * 32 + g * 8 + j;
            af[kt][j] = (k < F) ? (f16)xrow[k] : (f16)0.0f;
        }
    f32x4 acc[4] = {{0,0,0,0},{0,0,0,0},{0,0,0,0},{0,0,0,0}};
#pragma unroll
    for (int ct = 0; ct < 4; ++ct)
#pragma unroll
        for (int kt = 0; kt < KT; ++kt)
            acc[ct] = __builtin_amdgcn_mfma_f32_16x16x32_f16(af[kt], bf[ct][kt], acc[ct], 0, 0, 0);
#pragma unroll
    for (int q = 0; q < 4; ++q) {
        int r = r0 + g * 4 + q;
        long ebase = (long)nid[r] * Hc;
#pragma unroll
        for (int ct = 0; ct < 4; ++ct) {
            int col = ct * 16 + m;
            float v = acc[ct][q] + b[col] + emb[ebase + col];
            out[(long)r * Hc + col] = __float2half(v);
        }
    }
}

// ---- MFMA dense pair: T = in@wl^T (fp16); PRE = in@wr^T + br (fp16). ----
__global__ __launch_bounds__(256) void dense2_mfma(
        const __half* inU, const float* wlU, const float* brU, const float* wrU,
        __half* ToutU, __half* PREU,
        const __half* inR, const float* wlR, const float* brR, const float* wrR,
        __half* ToutR, __half* PRER) {
    int half = gridDim.x >> 1;
    bool isR = blockIdx.x >= half;
    const __half* in = isR ? inR : inU;
    const float* wl = isR ? wlR : wlU;
    const float* wr = isR ? wrR : wrU;
    const float* br = isR ? brR : brU;
    __half* Tout = isR ? ToutR : ToutU;
    __half* PRE  = isR ? PRER : PREU;
    int l = threadIdx.x & 63;
    int m = l & 15;
    int g = l >> 4;
    f16x8 bf[8][2];
#pragma unroll
    for (int ct = 0; ct < 4; ++ct)
#pragma unroll
        for (int kt = 0; kt < 2; ++kt)
#pragma unroll
            for (int j = 0; j < 8; ++j) {
                int k = kt * 32 + g * 8 + j;
                bf[ct][kt][j]     = (f16)wl[(ct * 16 + m) * Hc + k];
                bf[4 + ct][kt][j] = (f16)wr[(ct * 16 + m) * Hc + k];
            }
    int rt = (int)((((long)blockIdx.x - (isR ? half : 0)) * blockDim.x + threadIdx.x) >> 6);
    if (rt >= NTILE) return;
    int r0 = rt * 16;
    f16x8 af[2];
    const __half* irow = in + (long)(r0 + m) * Hc;
    af[0] = *(const f16x8*)(irow + g * 8);
    af[1] = *(const f16x8*)(irow + 32 + g * 8);
    f32x4 acc[8] = {{0,0,0,0},{0,0,0,0},{0,0,0,0},{0,0,0,0},
                    {0,0,0,0},{0,0,0,0},{0,0,0,0},{0,0,0,0}};
#pragma unroll
    for (int ct = 0; ct < 8; ++ct)
#pragma unroll
        for (int kt = 0; kt < 2; ++kt)
            acc[ct] = __builtin_amdgcn_mfma_f32_16x16x32_f16(af[kt], bf[ct][kt], acc[ct], 0, 0, 0);
#pragma unroll
    for (int q = 0; q < 4; ++q) {
        int r = r0 + g * 4 + q;
#pragma unroll
        for (int ct = 0; ct < 4; ++ct) {
            int col = ct * 16 + m;
            Tout[(long)r * Hc + col] = __float2half(acc[ct][q]);
            PRE[(long)r * Hc + col] = __float2half(acc[4 + ct][q] + br[col]);
        }
    }
}

// ---- gather pair, wide datapath: lane = (channel-oct o=l&7: 16B of row) x
//      (neighbor-slot p=l>>3: j = p mod 8). One dwordx4 load covers 8 rows.
//      2-deep unroll -> 2 independent 1KB loads in flight per wave. ----
__global__ __launch_bounds__(256) void gather_pair_kernel(
        const __half* __restrict__ TA, __half* __restrict__ ioA,
        const __half* __restrict__ TB, __half* __restrict__ ioB,
        const int* __restrict__ base, const int* __restrict__ cnt,
        const int* __restrict__ adj, int relu) {
    int l = threadIdx.x & 63;
    int o = l & 7;          // channel oct: channels [o*8, o*8+8)
    int p = l >> 3;         // neighbor slot 0..7
    bool isU = blockIdx.x >= GBS;
    int bid = blockIdx.x - (isU ? GBS : 0);
    int r = (int)(((long)bid * 256 + threadIdx.x) >> 6);
    int noff = isU ? NR : 0;
    const __half* T = isU ? TB : TA;
    __half* io = isU ? ioB : ioA;
    int b0 = base[noff + r], c = cnt[noff + r];
    __half2 z = __float2half2_rn(0.0f);
    __half2 s0 = z, s1 = z, s2 = z, s3 = z;
    __half2 t0 = z, t1 = z, t2 = z, t3 = z;
    int j = p;
    for (; j + 8 < c; j += 16) {
        int n0 = adj[b0 + j];
        int n1 = adj[b0 + j + 8];
        uint4 v0 = *(const uint4*)(T + (long)n0 * Hc + o * 8);
        uint4 v1 = *(const uint4*)(T + (long)n1 * Hc + o * 8);
        s0 = __hadd2(s0, *(__half2*)&v0.x); t0 = __hadd2(t0, *(__half2*)&v1.x);
        s1 = __hadd2(s1, *(__half2*)&v0.y); t1 = __hadd2(t1, *(__half2*)&v1.y);
        s2 = __hadd2(s2, *(__half2*)&v0.z); t2 = __hadd2(t2, *(__half2*)&v1.z);
        s3 = __hadd2(s3, *(__half2*)&v0.w); t3 = __hadd2(t3, *(__half2*)&v1.w);
    }
    if (j < c) {
        int n = adj[b0 + j];
        uint4 v = *(const uint4*)(T + (long)n * Hc + o * 8);
        s0 = __hadd2(s0, *(__half2*)&v.x);
        s1 = __hadd2(s1, *(__half2*)&v.y);
        s2 = __hadd2(s2, *(__half2*)&v.z);
        s3 = __hadd2(s3, *(__half2*)&v.w);
    }
    s0 = __hadd2(s0, t0); s1 = __hadd2(s1, t1);
    s2 = __hadd2(s2, t2); s3 = __hadd2(s3, t3);
#pragma unroll
    for (int m = 8; m <= 32; m <<= 1) {
        s0 = __hadd2(s0, shx2(s0, m));
        s1 = __hadd2(s1, shx2(s1, m));
        s2 = __hadd2(s2, shx2(s2, m));
        s3 = __hadd2(s3, shx2(s3, m));
    }
    if (p == 0) {
        float inv = 1.0f / fmaxf((float)c, 1.0f);
        __half* op = io + (long)r * Hc + o * 8;
        uint4 cur = *(const uint4*)op;
        __half2 acc[4] = {s0, s1, s2, s3};
        unsigned int* cw = &cur.x;
        uint4 outv;
        unsigned int* ow = &outv.x;
#pragma unroll
        for (int q = 0; q < 4; ++q) {
            float2 f = __half22float2(*(__half2*)&cw[q]);
            float2 a = __half22float2(acc[q]);
            float ox = f.x + a.x * inv;
            float oy = f.y + a.y * inv;
            if (relu) { ox = fmaxf(ox, 0.0f); oy = fmaxf(oy, 0.0f); }
            __half2 h = __floats2half2_rn(ox, oy);
            ow[q] = *(unsigned int*)&h;
        }
        *(uint4*)op = outv;
    }
}

// ---- edge dot-product classifier (fp16 H inputs, f32 out) ----
__global__ void edge_dot_kernel(const int* __restrict__ eli,
                                const __half* __restrict__ HU2, const __half* __restrict__ HR2,
                                float* __restrict__ out) {
    long gid = (long)blockIdx.x * blockDim.x + threadIdx.x;
    long e = gid >> 4;
    int t = (int)(gid & 15);
    if (e >= ELc) return;
    int a = eli[e], b = eli[ELc + e];
    const __half2* xa = (const __half2*)(HU2 + (long)a * Hc + t * 4);
    const __half2* yb = (const __half2*)(HR2 + (long)b * Hc + t * 4);
    float2 x0 = __half22float2(xa[0]), x1 = __half22float2(xa[1]);
    float2 y0 = __half22float2(yb[0]), y1 = __half22float2(yb[1]);
    float v = x0.x * y0.x + x0.y * y0.y + x1.x * y1.x + x1.y * y1.y;
    v += __shfl_xor(v, 1);
    v += __shfl_xor(v, 2);
    v += __shfl_xor(v, 4);
    v += __shfl_xor(v, 8);
    if (t == 0) out[e] = v;
}

extern "C" void kernel_launch(void* const* d_in, const int* in_sizes, int n_in,
                              void* d_out, int out_size, void* d_ws, size_t ws_size,
                              hipStream_t stream) {
    const float* x_user   = (const float*)d_in[0];
    const float* x_recipe = (const float*)d_in[1];
    const int*   user_nid = (const int*)d_in[2];
    const int*   rec_nid  = (const int*)d_in[3];
    const int*   edge_index = (const int*)d_in[4];
    const int*   edge_label = (const int*)d_in[5];
    const float* u_w   = (const float*)d_in[6];
    const float* u_b   = (const float*)d_in[7];
    const float* r_w   = (const float*)d_in[8];
    const float* r_b   = (const float*)d_in[9];
    const float* u_emb = (const float*)d_in[10];
    const float* r_emb = (const float*)d_in[11];
    const float* c1ra_wl = (const float*)d_in[12];
    const float* c1ra_bl = (const float*)d_in[13];
    const float* c1ra_wr = (const float*)d_in[14];
    const float* c1rv_wl = (const float*)d_in[15];
    const float* c1rv_bl = (const float*)d_in[16];
    const float* c1rv_wr = (const float*)d_in[17];
    const float* c2ra_wl = (const float*)d_in[18];
    const float* c2ra_bl = (const float*)d_in[19];
    const float* c2ra_wr = (const float*)d_in[20];
    const float* c2rv_wl = (const float*)d_in[21];
    const float* c2rv_bl = (const float*)d_in[22];
    const float* c2rv_wr = (const float*)d_in[23];

    const long NH = (long)NU * Hc;
    __half* B0 = (__half*)d_ws;      // XU -> PRE_U2 -> HU2
    __half* B1 = B0 + NH;            // XR -> PRE_R2 -> HR2
    __half* B2 = B1 + NH;            // rec alias -> PRE_U -> HU
    __half* B3 = B2 + NH;            // PRE_R -> HR
    __half* TAh = B3 + NH;           // fp16 T, user rows
    __half* TBh = TAh + NH;          // fp16 T, recipe rows
    int* cnt   = (int*)(TBh + NH);   // [NTOT]
    int* base  = cnt + NTOT;         // [NTOT]
    int* bcnt  = base + NTOT;        // [NBKT]
    int* bbase = bcnt + NBKT;        // [NBKT+1]
    int* bcur  = bbase + NBKT + 1;   // [NBKT]
    int* adj   = bcur + NBKT;        // [2*EE]
    int* rec = (int*)B2;             // 16MB alias (B2 is 19.2MB), dead before first B2 write

    // ---- CSR build via bucketed counting sort ----
    hipMemsetAsync(bcnt, 0, (size_t)NBKT * sizeof(int), stream);
    bucket_count_kernel<<<NCHUNK, 256, 0, stream>>>(edge_index, bcnt);
    bucket_scan_kernel<<<1, 256, 0, stream>>>(bcnt, bbase, bcur);
    scatter_records_kernel<<<NCHUNK, 256, 0, stream>>>(edge_index, bcur, rec);
    build_adj_kernel<<<NBKT, 256, 0, stream>>>(rec, bbase, adj, base, cnt);

    const int EB = (NTILE + 3) / 4;   // 2344 blocks (4 waves/block)
    // ---- encoders (MFMA): XU -> B0, XR -> B1 (fp16) ----
    encode_mfma<UF><<<EB, 256, 0, stream>>>(x_user, u_w, u_b, u_emb, user_nid, B0);
    encode_mfma<RF><<<EB, 256, 0, stream>>>(x_recipe, r_w, r_b, r_emb, rec_nid, B1);

    // ---- layer 1 dense pair (MFMA) ----
    dense2_mfma<<<2 * EB, 256, 0, stream>>>(
        B0, c1ra_wl, c1rv_bl, c1rv_wr, TAh, B2,
        B1, c1rv_wl, c1ra_bl, c1ra_wr, TBh, B3);

    // ---- layer 1 gathers: HR = relu(PRE_R + mean TU1) (B3); HU = relu(PRE_U + mean TR1) (B2)
    gather_pair_kernel<<<2 * GBS, 256, 0, stream>>>(TAh, B3, TBh, B2, base, cnt, adj, 1);

    // ---- layer 2 dense pair (MFMA) ----
    dense2_mfma<<<2 * EB, 256, 0, stream>>>(
        B2, c2ra_wl, c2rv_bl, c2rv_wr, TAh, B0,
        B3, c2rv_wl, c2ra_bl, c2ra_wr, TBh, B1);

    // ---- layer 2 gathers: HR2 = PRE_R2 + mean TU2 (B1); HU2 = PRE_U2 + mean TR2 (B0)
    gather_pair_kernel<<<2 * GBS, 256, 0, stream>>>(TAh, B1, TBh, B0, base, cnt, adj, 0);

    // ---- classifier: eli[0]=user -> HU2(B0), eli[1]=recipe -> HR2(B1) ----
    edge_dot_kernel<<<(ELc * 16) / 256, 256, 0, stream>>>(edge_label, B0, B1, (float*)d_out);
}

// Round 13
// 566.414 us; speedup vs baseline: 3.2828x; 1.1209x over previous
//
#include <hip/hip_runtime.h>
#include <hip/hip_fp16.h>

constexpr int NU = 150000;
constexpr int NR = 150000;
constexpr int Hc = 64;
constexpr int UF = 58;
constexpr int RF = 128;
constexpr long EE = 2000000;
constexpr long ELc = 500000;
constexpr int NTOT = NU + NR;            // combined ids: [0,NR)=recipes, [NR,NTOT)=users
constexpr int BKT = 256;
constexpr int NB_R = (NR + BKT - 1) / BKT;   // 586
constexpr int NB_U = (NU + BKT - 1) / BKT;   // 586
constexpr int NBKT = NB_R + NB_U;            // 1172
constexpr int CHUNK = 4096;
constexpr int NCHUNK = (int)((EE + CHUNK - 1) / CHUNK);  // 489
constexpr int NTILE = NU / 16;           // 9375 row-tiles (exact)
constexpr int GB8 = (NU / 8 + 3) / 4;    // gather blocks per side (4 waves, 32 dests/blk) = 4688

typedef _Float16 f16;
typedef f16 f16x8 __attribute__((ext_vector_type(8)));
typedef float f32x4 __attribute__((ext_vector_type(4)));

// ---- CSR build, pass 0: per-bucket edge counts (LDS-binned) ----
__global__ void bucket_count_kernel(const int* __restrict__ ei, int* __restrict__ bcnt) {
    __shared__ int lc[NBKT];
    for (int i = threadIdx.x; i < NBKT; i += 256) lc[i] = 0;
    __syncthreads();
    long e0 = (long)blockIdx.x * CHUNK;
    for (int k = threadIdx.x; k < CHUNK; k += 256) {
        long e = e0 + k;
        if (e < EE) {
            int u = ei[e], r = ei[EE + e];
            atomicAdd(&lc[r >> 8], 1);
            atomicAdd(&lc[NB_R + (u >> 8)], 1);
        }
    }
    __syncthreads();
    for (int i = threadIdx.x; i < NBKT; i += 256)
        if (lc[i]) atomicAdd(&bcnt[i], lc[i]);
}

// ---- pass 1: exclusive scan over NBKT bucket counts (single block) ----
__global__ void bucket_scan_kernel(const int* __restrict__ bcnt, int* __restrict__ bbase,
                                   int* __restrict__ bcur) {
    __shared__ int part[256];
    constexpr int PER = (NBKT + 255) / 256;   // 5
    int t = threadIdx.x;
    int loc[PER];
    int sum = 0;
    for (int j = 0; j < PER; ++j) {
        int i = t * PER + j;
        int v = (i < NBKT) ? bcnt[i] : 0;
        loc[j] = sum;
        sum += v;
    }
    part[t] = sum;
    __syncthreads();
    for (int off = 1; off < 256; off <<= 1) {
        int v = (t >= off) ? part[t - off] : 0;
        __syncthreads();
        part[t] += v;
        __syncthreads();
    }
    int pre = (t == 0) ? 0 : part[t - 1];
    for (int j = 0; j < PER; ++j) {
        int i = t * PER + j;
        if (i < NBKT) {
            int b = pre + loc[j];
            bbase[i] = b;
            bcur[i] = b;
        }
    }
    if (t == 255) bbase[NBKT] = part[255];
}

// ---- pass 2: chunked-reservation record scatter (4B records: local8|src18) ----
__global__ void scatter_records_kernel(const int* __restrict__ ei, int* __restrict__ bcur,
                                       int* __restrict__ rec) {
    __shared__ int lc[NBKT];
    for (int i = threadIdx.x; i < NBKT; i += 256) lc[i] = 0;
    __syncthreads();
    long e0 = (long)blockIdx.x * CHUNK;
    for (int k = threadIdx.x; k < CHUNK; k += 256) {
        long e = e0 + k;
        if (e < EE) {
            int u = ei[e], r = ei[EE + e];
            atomicAdd(&lc[r >> 8], 1);
            atomicAdd(&lc[NB_R + (u >> 8)], 1);
        }
    }
    __syncthreads();
    for (int i = threadIdx.x; i < NBKT; i += 256) {
        int c = lc[i];
        lc[i] = c ? atomicAdd(&bcur[i], c) : 0;   // reserve contiguous range
    }
    __syncthreads();
    for (int k = threadIdx.x; k < CHUNK; k += 256) {
        long e = e0 + k;
        if (e < EE) {
            int u = ei[e], r = ei[EE + e];
            int p1 = atomicAdd(&lc[r >> 8], 1);
            rec[p1] = ((r & 255) << 18) | u;
            int p2 = atomicAdd(&lc[NB_R + (u >> 8)], 1);
            rec[p2] = ((u & 255) << 18) | r;
        }
    }
}

// ---- pass 3: per-bucket counting sort -> adj (+ per-node base/cnt) ----
__global__ void build_adj_kernel(const int* __restrict__ rec, const int* __restrict__ bbase,
                                 int* __restrict__ adj, int* __restrict__ base,
                                 int* __restrict__ cnt) {
    __shared__ int c256[BKT];
    __shared__ int off256[BKT];
    int b = blockIdx.x;
    int s = bbase[b], e = bbase[b + 1];
    int t = threadIdx.x;
    c256[t] = 0;
    __syncthreads();
    for (int k = s + t; k < e; k += 256) atomicAdd(&c256[rec[k] >> 18], 1);
    __syncthreads();
    int v = c256[t];
    off256[t] = v;
    __syncthreads();
    for (int off = 1; off < 256; off <<= 1) {
        int x = (t >= off) ? off256[t - off] : 0;
        __syncthreads();
        off256[t] += x;
        __syncthreads();
    }
    int excl = off256[t] - v;
    bool isU = (b >= NB_R);
    int node = (isU ? (b - NB_R) : b) * BKT + t;
    int lim = isU ? NU : NR;
    if (node < lim) {
        int cid = isU ? (NR + node) : node;
        base[cid] = s + excl;
        cnt[cid] = v;
    }
    c256[t] = s + excl;    // cursors
    __syncthreads();
    for (int k = s + t; k < e; k += 256) {
        int rv = rec[k];
        int p = atomicAdd(&c256[rv >> 18], 1);
        adj[p] = rv & 0x3FFFF;
    }
}

// ---- MFMA node encoder: out(fp16) = x@W^T + b + emb[nid]. ----
template <int F>
__global__ __launch_bounds__(256) void encode_mfma(
        const float* __restrict__ xin, const float* __restrict__ w,   // w [64][F]
        const float* __restrict__ b, const float* __restrict__ emb,
        const int* __restrict__ nid, __half* __restrict__ out) {
    constexpr int KT = (F + 31) / 32;
    int l = threadIdx.x & 63;
    int m = l & 15;
    int g = l >> 4;
    f16x8 bf[4][KT];
#pragma unroll
    for (int ct = 0; ct < 4; ++ct)
#pragma unroll
        for (int kt = 0; kt < KT; ++kt)
#pragma unroll
            for (int j = 0; j < 8; ++j) {
                int k = kt * 32 + g * 8 + j;
                bf[ct][kt][j] = (k < F) ? (f16)w[(ct * 16 + m) * F + k] : (f16)0.0f;
            }
    int rt = (int)(((long)blockIdx.x * blockDim.x + threadIdx.x) >> 6);
    if (rt >= NTILE) return;
    int r0 = rt * 16;
    f16x8 af[KT];
    const float* xrow = xin + (long)(r0 + m) * F;
#pragma unroll
    for (int kt = 0; kt < KT; ++kt)
#pragma unroll
        for (int j = 0; j < 8; ++j) {
            int k = kt * 32 + g * 8 + j;
            af[kt][j] = (k < F) ? (f16)xrow[k] : (f16)0.0f;
        }
    f32x4 acc[4] = {{0,0,0,0},{0,0,0,0},{0,0,0,0},{0,0,0,0}};
#pragma unroll
    for (int ct = 0; ct < 4; ++ct)
#pragma unroll
        for (int kt = 0; kt < KT; ++kt)
            acc[ct] = __builtin_amdgcn_mfma_f32_16x16x32_f16(af[kt], bf[ct][kt], acc[ct], 0, 0, 0);
#pragma unroll
    for (int q = 0; q < 4; ++q) {
        int r = r0 + g * 4 + q;
        long ebase = (long)nid[r] * Hc;
#pragma unroll
        for (int ct = 0; ct < 4; ++ct) {
            int col = ct * 16 + m;
            float v = acc[ct][q] + b[col] + emb[ebase + col];
            out[(long)r * Hc + col] = __float2half(v);
        }
    }
}

// ---- MFMA dense pair: T = in@wl^T (fp16); PRE = in@wr^T + br (fp16). ----
__global__ __launch_bounds__(256) void dense2_mfma(
        const __half* inU, const float* wlU, const float* brU, const float* wrU,
        __half* ToutU, __half* PREU,
        const __half* inR, const float* wlR, const float* brR, const float* wrR,
        __half* ToutR, __half* PRER) {
    int half = gridDim.x >> 1;
    bool isR = blockIdx.x >= half;
    const __half* in = isR ? inR : inU;
    const float* wl = isR ? wlR : wlU;
    const float* wr = isR ? wrR : wrU;
    const float* br = isR ? brR : brU;
    __half* Tout = isR ? ToutR : ToutU;
    __half* PRE  = isR ? PRER : PREU;
    int l = threadIdx.x & 63;
    int m = l & 15;
    int g = l >> 4;
    f16x8 bf[8][2];
#pragma unroll
    for (int ct = 0; ct < 4; ++ct)
#pragma unroll
        for (int kt = 0; kt < 2; ++kt)
#pragma unroll
            for (int j = 0; j < 8; ++j) {
                int k = kt * 32 + g * 8 + j;
                bf[ct][kt][j]     = (f16)wl[(ct * 16 + m) * Hc + k];
                bf[4 + ct][kt][j] = (f16)wr[(ct * 16 + m) * Hc + k];
            }
    int rt = (int)((((long)blockIdx.x - (isR ? half : 0)) * blockDim.x + threadIdx.x) >> 6);
    if (rt >= NTILE) return;
    int r0 = rt * 16;
    f16x8 af[2];
    const __half* irow = in + (long)(r0 + m) * Hc;
    af[0] = *(const f16x8*)(irow + g * 8);
    af[1] = *(const f16x8*)(irow + 32 + g * 8);
    f32x4 acc[8] = {{0,0,0,0},{0,0,0,0},{0,0,0,0},{0,0,0,0},
                    {0,0,0,0},{0,0,0,0},{0,0,0,0},{0,0,0,0}};
#pragma unroll
    for (int ct = 0; ct < 8; ++ct)
#pragma unroll
        for (int kt = 0; kt < 2; ++kt)
            acc[ct] = __builtin_amdgcn_mfma_f32_16x16x32_f16(af[kt], bf[ct][kt], acc[ct], 0, 0, 0);
#pragma unroll
    for (int q = 0; q < 4; ++q) {
        int r = r0 + g * 4 + q;
#pragma unroll
        for (int ct = 0; ct < 4; ++ct) {
            int col = ct * 16 + m;
            Tout[(long)r * Hc + col] = __float2half(acc[ct][q]);
            PRE[(long)r * Hc + col] = __float2half(acc[4 + ct][q] + br[col]);
        }
    }
}

// ---- gather, no cross-lane reduce: wave = 8 destinations; lane = (dest-group
//      d=l>>3) x (channel-oct o=l&7, 16B of row). Each lane serially sums its
//      16B slice over its dest's neighbors (2-deep unroll), then RMWs io. ----
__global__ __launch_bounds__(256) void gather8_kernel(
        const __half* __restrict__ TA, __half* __restrict__ ioA,
        const __half* __restrict__ TB, __half* __restrict__ ioB,
        const int* __restrict__ base, const int* __restrict__ cnt,
        const int* __restrict__ adj, int relu) {
    int l = threadIdx.x & 63;
    int d = l >> 3;          // dest group
    int o = l & 7;           // channel oct: channels [o*8, o*8+8)
    int half = gridDim.x >> 1;
    bool isU = blockIdx.x >= half;
    int bid = blockIdx.x - (isU ? half : 0);
    int wid = bid * 4 + (threadIdx.x >> 6);
    int r = wid * 8 + d;
    if (r >= NU) return;
    int noff = isU ? NR : 0;
    const __half* T = isU ? TB : TA;
    __half* io = isU ? ioB : ioA;
    int b0 = base[noff + r], c = cnt[noff + r];
    int co = o * 8;
    __half2 z = __float2half2_rn(0.0f);
    __half2 s0 = z, s1 = z, s2 = z, s3 = z;
    __half2 t0 = z, t1 = z, t2 = z, t3 = z;
    int j = 0;
    for (; j + 1 < c; j += 2) {
        int n0 = adj[b0 + j];
        int n1 = adj[b0 + j + 1];
        uint4 v0 = *(const uint4*)(T + n0 * Hc + co);
        uint4 v1 = *(const uint4*)(T + n1 * Hc + co);
        s0 = __hadd2(s0, *(__half2*)&v0.x); t0 = __hadd2(t0, *(__half2*)&v1.x);
        s1 = __hadd2(s1, *(__half2*)&v0.y); t1 = __hadd2(t1, *(__half2*)&v1.y);
        s2 = __hadd2(s2, *(__half2*)&v0.z); t2 = __hadd2(t2, *(__half2*)&v1.z);
        s3 = __hadd2(s3, *(__half2*)&v0.w); t3 = __hadd2(t3, *(__half2*)&v1.w);
    }
    if (j < c) {
        int n = adj[b0 + j];
        uint4 v = *(const uint4*)(T + n * Hc + co);
        s0 = __hadd2(s0, *(__half2*)&v.x);
        s1 = __hadd2(s1, *(__half2*)&v.y);
        s2 = __hadd2(s2, *(__half2*)&v.z);
        s3 = __hadd2(s3, *(__half2*)&v.w);
    }
    s0 = __hadd2(s0, t0); s1 = __hadd2(s1, t1);
    s2 = __hadd2(s2, t2); s3 = __hadd2(s3, t3);
    float inv = 1.0f / fmaxf((float)c, 1.0f);
    __half* op = io + (long)r * Hc + co;
    uint4 cur = *(const uint4*)op;
    __half2 acc[4] = {s0, s1, s2, s3};
    unsigned int* cw = &cur.x;
    uint4 outv;
    unsigned int* ow = &outv.x;
#pragma unroll
    for (int q = 0; q < 4; ++q) {
        float2 f = __half22float2(*(__half2*)&cw[q]);
        float2 a = __half22float2(acc[q]);
        float ox = f.x + a.x * inv;
        float oy = f.y + a.y * inv;
        if (relu) { ox = fmaxf(ox, 0.0f); oy = fmaxf(oy, 0.0f); }
        __half2 h = __floats2half2_rn(ox, oy);
        ow[q] = *(unsigned int*)&h;
    }
    *(uint4*)op = outv;
}

// ---- edge dot-product classifier (fp16 H inputs, f32 out) ----
__global__ void edge_dot_kernel(const int* __restrict__ eli,
                                const __half* __restrict__ HU2, const __half* __restrict__ HR2,
                                float* __restrict__ out) {
    long gid = (long)blockIdx.x * blockDim.x + threadIdx.x;
    long e = gid >> 4;
    int t = (int)(gid & 15);
    if (e >= ELc) return;
    int a = eli[e], b = eli[ELc + e];
    const __half2* xa = (const __half2*)(HU2 + (long)a * Hc + t * 4);
    const __half2* yb = (const __half2*)(HR2 + (long)b * Hc + t * 4);
    float2 x0 = __half22float2(xa[0]), x1 = __half22float2(xa[1]);
    float2 y0 = __half22float2(yb[0]), y1 = __half22float2(yb[1]);
    float v = x0.x * y0.x + x0.y * y0.y + x1.x * y1.x + x1.y * y1.y;
    v += __shfl_xor(v, 1);
    v += __shfl_xor(v, 2);
    v += __shfl_xor(v, 4);
    v += __shfl_xor(v, 8);
    if (t == 0) out[e] = v;
}

extern "C" void kernel_launch(void* const* d_in, const int* in_sizes, int n_in,
                              void* d_out, int out_size, void* d_ws, size_t ws_size,
                              hipStream_t stream) {
    const float* x_user   = (const float*)d_in[0];
    const float* x_recipe = (const float*)d_in[1];
    const int*   user_nid = (const int*)d_in[2];
    const int*   rec_nid  = (const int*)d_in[3];
    const int*   edge_index = (const int*)d_in[4];
    const int*   edge_label = (const int*)d_in[5];
    const float* u_w   = (const float*)d_in[6];
    const float* u_b   = (const float*)d_in[7];
    const float* r_w   = (const float*)d_in[8];
    const float* r_b   = (const float*)d_in[9];
    const float* u_emb = (const float*)d_in[10];
    const float* r_emb = (const float*)d_in[11];
    const float* c1ra_wl = (const float*)d_in[12];
    const float* c1ra_bl = (const float*)d_in[13];
    const float* c1ra_wr = (const float*)d_in[14];
    const float* c1rv_wl = (const float*)d_in[15];
    const float* c1rv_bl = (const float*)d_in[16];
    const float* c1rv_wr = (const float*)d_in[17];
    const float* c2ra_wl = (const float*)d_in[18];
    const float* c2ra_bl = (const float*)d_in[19];
    const float* c2ra_wr = (const float*)d_in[20];
    const float* c2rv_wl = (const float*)d_in[21];
    const float* c2rv_bl = (const float*)d_in[22];
    const float* c2rv_wr = (const float*)d_in[23];

    const long NH = (long)NU * Hc;
    __half* B0 = (__half*)d_ws;      // XU -> PRE_U2 -> HU2
    __half* B1 = B0 + NH;            // XR -> PRE_R2 -> HR2
    __half* B2 = B1 + NH;            // rec alias -> PRE_U -> HU
    __half* B3 = B2 + NH;            // PRE_R -> HR
    __half* TAh = B3 + NH;           // fp16 T, user rows
    __half* TBh = TAh + NH;          // fp16 T, recipe rows
    int* cnt   = (int*)(TBh + NH);   // [NTOT]
    int* base  = cnt + NTOT;         // [NTOT]
    int* bcnt  = base + NTOT;        // [NBKT]
    int* bbase = bcnt + NBKT;        // [NBKT+1]
    int* bcur  = bbase + NBKT + 1;   // [NBKT]
    int* adj   = bcur + NBKT;        // [2*EE]
    int* rec = (int*)B2;             // 16MB alias (B2 is 19.2MB), dead before first B2 write

    // ---- CSR build via bucketed counting sort ----
    hipMemsetAsync(bcnt, 0, (size_t)NBKT * sizeof(int), stream);
    bucket_count_kernel<<<NCHUNK, 256, 0, stream>>>(edge_index, bcnt);
    bucket_scan_kernel<<<1, 256, 0, stream>>>(bcnt, bbase, bcur);
    scatter_records_kernel<<<NCHUNK, 256, 0, stream>>>(edge_index, bcur, rec);
    build_adj_kernel<<<NBKT, 256, 0, stream>>>(rec, bbase, adj, base, cnt);

    const int EB = (NTILE + 3) / 4;   // 2344 blocks (4 waves/block)
    // ---- encoders (MFMA): XU -> B0, XR -> B1 (fp16) ----
    encode_mfma<UF><<<EB, 256, 0, stream>>>(x_user, u_w, u_b, u_emb, user_nid, B0);
    encode_mfma<RF><<<EB, 256, 0, stream>>>(x_recipe, r_w, r_b, r_emb, rec_nid, B1);

    // ---- layer 1 dense pair (MFMA) ----
    dense2_mfma<<<2 * EB, 256, 0, stream>>>(
        B0, c1ra_wl, c1rv_bl, c1rv_wr, TAh, B2,
        B1, c1rv_wl, c1ra_bl, c1ra_wr, TBh, B3);

    // ---- layer 1 gathers: HR = relu(PRE_R + mean TU1) (B3); HU = relu(PRE_U + mean TR1) (B2)
    gather8_kernel<<<2 * GB8, 256, 0, stream>>>(TAh, B3, TBh, B2, base, cnt, adj, 1);

    // ---- layer 2 dense pair (MFMA) ----
    dense2_mfma<<<2 * EB, 256, 0, stream>>>(
        B2, c2ra_wl, c2rv_bl, c2rv_wr, TAh, B0,
        B3, c2rv_wl, c2ra_bl, c2ra_wr, TBh, B1);

    // ---- layer 2 gathers: HR2 = PRE_R2 + mean TU2 (B1); HU2 = PRE_U2 + mean TR2 (B0)
    gather8_kernel<<<2 * GB8, 256, 0, stream>>>(TAh, B1, TBh, B0, base, cnt, adj, 0);

    // ---- classifier: eli[0]=user -> HU2(B0), eli[1]=recipe -> HR2(B1) ----
    edge_dot_kernel<<<(ELc * 16) / 256, 256, 0, stream>>>(edge_label, B0, B1, (float*)d_out);
}

// Round 14
// 409.946 us; speedup vs baseline: 4.5358x; 1.3817x over previous
//
#include <hip/hip_runtime.h>
#include <hip/hip_fp16.h>

constexpr int NU = 150000;
constexpr int NR = 150000;
constexpr int Hc = 64;
constexpr int UF = 58;
constexpr int RF = 128;
constexpr long EE = 2000000;
constexpr long ELc = 500000;
constexpr int NTOT = NU + NR;            // combined ids: [0,NR)=recipes, [NR,NTOT)=users
constexpr int BKT = 256;
constexpr int NB_R = (NR + BKT - 1) / BKT;   // 586
constexpr int NB_U = (NU + BKT - 1) / BKT;   // 586
constexpr int NBKT = NB_R + NB_U;            // 1172
constexpr int CHUNK = 4096;
constexpr int NCHUNK = (int)((EE + CHUNK - 1) / CHUNK);  // 489
constexpr int NTILE = NU / 16;           // 9375 row-tiles (exact)
constexpr int GB8 = (NU / 8 + 3) / 4;    // gather blocks per side (4 waves, 32 dests/blk) = 4688

typedef _Float16 f16;
typedef f16 f16x8 __attribute__((ext_vector_type(8)));
typedef float f32x4 __attribute__((ext_vector_type(4)));

// ---- CSR build, pass 0: per-bucket edge counts (LDS-binned) ----
__global__ void bucket_count_kernel(const int* __restrict__ ei, int* __restrict__ bcnt) {
    __shared__ int lc[NBKT];
    for (int i = threadIdx.x; i < NBKT; i += 256) lc[i] = 0;
    __syncthreads();
    long e0 = (long)blockIdx.x * CHUNK;
    for (int k = threadIdx.x; k < CHUNK; k += 256) {
        long e = e0 + k;
        if (e < EE) {
            int u = ei[e], r = ei[EE + e];
            atomicAdd(&lc[r >> 8], 1);
            atomicAdd(&lc[NB_R + (u >> 8)], 1);
        }
    }
    __syncthreads();
    for (int i = threadIdx.x; i < NBKT; i += 256)
        if (lc[i]) atomicAdd(&bcnt[i], lc[i]);
}

// ---- pass 1: exclusive scan over NBKT bucket counts (single block) ----
__global__ void bucket_scan_kernel(const int* __restrict__ bcnt, int* __restrict__ bbase,
                                   int* __restrict__ bcur) {
    __shared__ int part[256];
    constexpr int PER = (NBKT + 255) / 256;   // 5
    int t = threadIdx.x;
    int loc[PER];
    int sum = 0;
    for (int j = 0; j < PER; ++j) {
        int i = t * PER + j;
        int v = (i < NBKT) ? bcnt[i] : 0;
        loc[j] = sum;
        sum += v;
    }
    part[t] = sum;
    __syncthreads();
    for (int off = 1; off < 256; off <<= 1) {
        int v = (t >= off) ? part[t - off] : 0;
        __syncthreads();
        part[t] += v;
        __syncthreads();
    }
    int pre = (t == 0) ? 0 : part[t - 1];
    for (int j = 0; j < PER; ++j) {
        int i = t * PER + j;
        if (i < NBKT) {
            int b = pre + loc[j];
            bbase[i] = b;
            bcur[i] = b;
        }
    }
    if (t == 255) bbase[NBKT] = part[255];
}

// ---- pass 2: chunked-reservation record scatter (4B records: local8|src18) ----
__global__ void scatter_records_kernel(const int* __restrict__ ei, int* __restrict__ bcur,
                                       int* __restrict__ rec) {
    __shared__ int lc[NBKT];
    for (int i = threadIdx.x; i < NBKT; i += 256) lc[i] = 0;
    __syncthreads();
    long e0 = (long)blockIdx.x * CHUNK;
    for (int k = threadIdx.x; k < CHUNK; k += 256) {
        long e = e0 + k;
        if (e < EE) {
            int u = ei[e], r = ei[EE + e];
            atomicAdd(&lc[r >> 8], 1);
            atomicAdd(&lc[NB_R + (u >> 8)], 1);
        }
    }
    __syncthreads();
    for (int i = threadIdx.x; i < NBKT; i += 256) {
        int c = lc[i];
        lc[i] = c ? atomicAdd(&bcur[i], c) : 0;   // reserve contiguous range
    }
    __syncthreads();
    for (int k = threadIdx.x; k < CHUNK; k += 256) {
        long e = e0 + k;
        if (e < EE) {
            int u = ei[e], r = ei[EE + e];
            int p1 = atomicAdd(&lc[r >> 8], 1);
            rec[p1] = ((r & 255) << 18) | u;
            int p2 = atomicAdd(&lc[NB_R + (u >> 8)], 1);
            rec[p2] = ((u & 255) << 18) | r;
        }
    }
}

// ---- pass 3: per-bucket counting sort -> adj (+ per-node base/cnt) ----
__global__ void build_adj_kernel(const int* __restrict__ rec, const int* __restrict__ bbase,
                                 int* __restrict__ adj, int* __restrict__ base,
                                 int* __restrict__ cnt) {
    __shared__ int c256[BKT];
    __shared__ int off256[BKT];
    int b = blockIdx.x;
    int s = bbase[b], e = bbase[b + 1];
    int t = threadIdx.x;
    c256[t] = 0;
    __syncthreads();
    for (int k = s + t; k < e; k += 256) atomicAdd(&c256[rec[k] >> 18], 1);
    __syncthreads();
    int v = c256[t];
    off256[t] = v;
    __syncthreads();
    for (int off = 1; off < 256; off <<= 1) {
        int x = (t >= off) ? off256[t - off] : 0;
        __syncthreads();
        off256[t] += x;
        __syncthreads();
    }
    int excl = off256[t] - v;
    bool isU = (b >= NB_R);
    int node = (isU ? (b - NB_R) : b) * BKT + t;
    int lim = isU ? NU : NR;
    if (node < lim) {
        int cid = isU ? (NR + node) : node;
        base[cid] = s + excl;
        cnt[cid] = v;
    }
    c256[t] = s + excl;    // cursors
    __syncthreads();
    for (int k = s + t; k < e; k += 256) {
        int rv = rec[k];
        int p = atomicAdd(&c256[rv >> 18], 1);
        adj[p] = rv & 0x3FFFF;
    }
}

// ---- MFMA node encoder, LDS-staged weights + grid-stride tile reuse:
//      out(fp16) = x@W^T + b + emb[nid]. ----
template <int F>
__global__ __launch_bounds__(256) void encode_mfma(
        const float* __restrict__ xin, const float* __restrict__ w,   // w [64][F]
        const float* __restrict__ b, const float* __restrict__ emb,
        const int* __restrict__ nid, __half* __restrict__ out) {
    constexpr int KT = (F + 31) / 32;
    __shared__ f16 wlds[Hc * F];
    for (int i = threadIdx.x; i < Hc * F; i += 256) wlds[i] = (f16)w[i];
    __syncthreads();
    int l = threadIdx.x & 63;
    int m = l & 15;
    int g = l >> 4;
    f16x8 bf[4][KT];
#pragma unroll
    for (int ct = 0; ct < 4; ++ct)
#pragma unroll
        for (int kt = 0; kt < KT; ++kt)
#pragma unroll
            for (int j = 0; j < 8; ++j) {
                int k = kt * 32 + g * 8 + j;
                bf[ct][kt][j] = (k < F) ? wlds[(ct * 16 + m) * F + k] : (f16)0.0f;
            }
    float bv[4];
#pragma unroll
    for (int ct = 0; ct < 4; ++ct) bv[ct] = b[ct * 16 + m];
    int wid0 = (int)(((long)blockIdx.x * 256 + threadIdx.x) >> 6);
    int nw = (gridDim.x * 256) >> 6;
    for (int rt = wid0; rt < NTILE; rt += nw) {
        int r0 = rt * 16;
        const float* xrow = xin + (long)(r0 + m) * F;
        f16x8 af[KT];
#pragma unroll
        for (int kt = 0; kt < KT; ++kt)
#pragma unroll
            for (int jj = 0; jj < 4; ++jj) {
                int k = kt * 32 + g * 8 + jj * 2;
                if (k + 1 < F) {
                    float2 v = *(const float2*)(xrow + k);
                    af[kt][jj * 2] = (f16)v.x;
                    af[kt][jj * 2 + 1] = (f16)v.y;
                } else {
                    af[kt][jj * 2] = (k < F) ? (f16)xrow[k] : (f16)0.0f;
                    af[kt][jj * 2 + 1] = (f16)0.0f;
                }
            }
        f32x4 acc[4] = {{0,0,0,0},{0,0,0,0},{0,0,0,0},{0,0,0,0}};
#pragma unroll
        for (int ct = 0; ct < 4; ++ct)
#pragma unroll
            for (int kt = 0; kt < KT; ++kt)
                acc[ct] = __builtin_amdgcn_mfma_f32_16x16x32_f16(af[kt], bf[ct][kt], acc[ct], 0, 0, 0);
#pragma unroll
        for (int q = 0; q < 4; ++q) {
            int r = r0 + g * 4 + q;
            long ebase = (long)nid[r] * Hc;
#pragma unroll
            for (int ct = 0; ct < 4; ++ct) {
                int col = ct * 16 + m;
                float v = acc[ct][q] + bv[ct] + emb[ebase + col];
                out[(long)r * Hc + col] = __float2half(v);
            }
        }
    }
}

// ---- MFMA dense pair, LDS-staged weights + grid-stride tile reuse:
//      T = in@wl^T (fp16); PRE = in@wr^T + br (fp16). ----
__global__ __launch_bounds__(256) void dense2_mfma(
        const __half* inU, const float* wlU, const float* brU, const float* wrU,
        __half* ToutU, __half* PREU,
        const __half* inR, const float* wlR, const float* brR, const float* wrR,
        __half* ToutR, __half* PRER) {
    __shared__ f16 wlds[2][Hc * Hc];
    int half = gridDim.x >> 1;
    bool isR = blockIdx.x >= half;
    const __half* in = isR ? inR : inU;
    const float* wl = isR ? wlR : wlU;
    const float* wr = isR ? wrR : wrU;
    const float* br = isR ? brR : brU;
    __half* Tout = isR ? ToutR : ToutU;
    __half* PRE  = isR ? PRER : PREU;
    for (int i = threadIdx.x; i < Hc * Hc; i += 256) {
        wlds[0][i] = (f16)wl[i];
        wlds[1][i] = (f16)wr[i];
    }
    __syncthreads();
    int l = threadIdx.x & 63;
    int m = l & 15;
    int g = l >> 4;
    f16x8 bf[8][2];
#pragma unroll
    for (int ct = 0; ct < 4; ++ct)
#pragma unroll
        for (int kt = 0; kt < 2; ++kt) {
            bf[ct][kt]     = *(const f16x8*)&wlds[0][(ct * 16 + m) * Hc + kt * 32 + g * 8];
            bf[4 + ct][kt] = *(const f16x8*)&wlds[1][(ct * 16 + m) * Hc + kt * 32 + g * 8];
        }
    float bv[4];
#pragma unroll
    for (int ct = 0; ct < 4; ++ct) bv[ct] = br[ct * 16 + m];
    int wid0 = (int)((((long)blockIdx.x - (isR ? half : 0)) * 256 + threadIdx.x) >> 6);
    int nw = (half * 256) >> 6;
    for (int rt = wid0; rt < NTILE; rt += nw) {
        int r0 = rt * 16;
        f16x8 af[2];
        const __half* irow = in + (long)(r0 + m) * Hc;
        af[0] = *(const f16x8*)(irow + g * 8);
        af[1] = *(const f16x8*)(irow + 32 + g * 8);
        f32x4 acc[8] = {{0,0,0,0},{0,0,0,0},{0,0,0,0},{0,0,0,0},
                        {0,0,0,0},{0,0,0,0},{0,0,0,0},{0,0,0,0}};
#pragma unroll
        for (int ct = 0; ct < 8; ++ct)
#pragma unroll
            for (int kt = 0; kt < 2; ++kt)
                acc[ct] = __builtin_amdgcn_mfma_f32_16x16x32_f16(af[kt], bf[ct][kt], acc[ct], 0, 0, 0);
#pragma unroll
        for (int q = 0; q < 4; ++q) {
            int r = r0 + g * 4 + q;
#pragma unroll
            for (int ct = 0; ct < 4; ++ct) {
                int col = ct * 16 + m;
                Tout[(long)r * Hc + col] = __float2half(acc[ct][q]);
                PRE[(long)r * Hc + col] = __float2half(acc[4 + ct][q] + bv[ct]);
            }
        }
    }
}

// ---- gather, no cross-lane reduce: wave = 8 destinations; lane = (dest-group
//      d=l>>3) x (channel-oct o=l&7, 16B of row). ----
__global__ __launch_bounds__(256) void gather8_kernel(
        const __half* __restrict__ TA, __half* __restrict__ ioA,
        const __half* __restrict__ TB, __half* __restrict__ ioB,
        const int* __restrict__ base, const int* __restrict__ cnt,
        const int* __restrict__ adj, int relu) {
    int l = threadIdx.x & 63;
    int d = l >> 3;          // dest group
    int o = l & 7;           // channel oct: channels [o*8, o*8+8)
    int half = gridDim.x >> 1;
    bool isU = blockIdx.x >= half;
    int bid = blockIdx.x - (isU ? half : 0);
    int wid = bid * 4 + (threadIdx.x >> 6);
    int r = wid * 8 + d;
    if (r >= NU) return;
    int noff = isU ? NR : 0;
    const __half* T = isU ? TB : TA;
    __half* io = isU ? ioB : ioA;
    int b0 = base[noff + r], c = cnt[noff + r];
    int co = o * 8;
    __half2 z = __float2half2_rn(0.0f);
    __half2 s0 = z, s1 = z, s2 = z, s3 = z;
    __half2 t0 = z, t1 = z, t2 = z, t3 = z;
    int j = 0;
    for (; j + 1 < c; j += 2) {
        int n0 = adj[b0 + j];
        int n1 = adj[b0 + j + 1];
        uint4 v0 = *(const uint4*)(T + n0 * Hc + co);
        uint4 v1 = *(const uint4*)(T + n1 * Hc + co);
        s0 = __hadd2(s0, *(__half2*)&v0.x); t0 = __hadd2(t0, *(__half2*)&v1.x);
        s1 = __hadd2(s1, *(__half2*)&v0.y); t1 = __hadd2(t1, *(__half2*)&v1.y);
        s2 = __hadd2(s2, *(__half2*)&v0.z); t2 = __hadd2(t2, *(__half2*)&v1.z);
        s3 = __hadd2(s3, *(__half2*)&v0.w); t3 = __hadd2(t3, *(__half2*)&v1.w);
    }
    if (j < c) {
        int n = adj[b0 + j];
        uint4 v = *(const uint4*)(T + n * Hc + co);
        s0 = __hadd2(s0, *(__half2*)&v.x);
        s1 = __hadd2(s1, *(__half2*)&v.y);
        s2 = __hadd2(s2, *(__half2*)&v.z);
        s3 = __hadd2(s3, *(__half2*)&v.w);
    }
    s0 = __hadd2(s0, t0); s1 = __hadd2(s1, t1);
    s2 = __hadd2(s2, t2); s3 = __hadd2(s3, t3);
    float inv = 1.0f / fmaxf((float)c, 1.0f);
    __half* op = io + (long)r * Hc + co;
    uint4 cur = *(const uint4*)op;
    __half2 acc[4] = {s0, s1, s2, s3};
    unsigned int* cw = &cur.x;
    uint4 outv;
    unsigned int* ow = &outv.x;
#pragma unroll
    for (int q = 0; q < 4; ++q) {
        float2 f = __half22float2(*(__half2*)&cw[q]);
        float2 a = __half22float2(acc[q]);
        float ox = f.x + a.x * inv;
        float oy = f.y + a.y * inv;
        if (relu) { ox = fmaxf(ox, 0.0f); oy = fmaxf(oy, 0.0f); }
        __half2 h = __floats2half2_rn(ox, oy);
        ow[q] = *(unsigned int*)&h;
    }
    *(uint4*)op = outv;
}

// ---- edge dot-product classifier (fp16 H inputs, f32 out) ----
__global__ void edge_dot_kernel(const int* __restrict__ eli,
                                const __half* __restrict__ HU2, const __half* __restrict__ HR2,
                                float* __restrict__ out) {
    long gid = (long)blockIdx.x * blockDim.x + threadIdx.x;
    long e = gid >> 4;
    int t = (int)(gid & 15);
    if (e >= ELc) return;
    int a = eli[e], b = eli[ELc + e];
    const __half2* xa = (const __half2*)(HU2 + (long)a * Hc + t * 4);
    const __half2* yb = (const __half2*)(HR2 + (long)b * Hc + t * 4);
    float2 x0 = __half22float2(xa[0]), x1 = __half22float2(xa[1]);
    float2 y0 = __half22float2(yb[0]), y1 = __half22float2(yb[1]);
    float v = x0.x * y0.x + x0.y * y0.y + x1.x * y1.x + x1.y * y1.y;
    v += __shfl_xor(v, 1);
    v += __shfl_xor(v, 2);
    v += __shfl_xor(v, 4);
    v += __shfl_xor(v, 8);
    if (t == 0) out[e] = v;
}

extern "C" void kernel_launch(void* const* d_in, const int* in_sizes, int n_in,
                              void* d_out, int out_size, void* d_ws, size_t ws_size,
                              hipStream_t stream) {
    const float* x_user   = (const float*)d_in[0];
    const float* x_recipe = (const float*)d_in[1];
    const int*   user_nid = (const int*)d_in[2];
    const int*   rec_nid  = (const int*)d_in[3];
    const int*   edge_index = (const int*)d_in[4];
    const int*   edge_label = (const int*)d_in[5];
    const float* u_w   = (const float*)d_in[6];
    const float* u_b   = (const float*)d_in[7];
    const float* r_w   = (const float*)d_in[8];
    const float* r_b   = (const float*)d_in[9];
    const float* u_emb = (const float*)d_in[10];
    const float* r_emb = (const float*)d_in[11];
    const float* c1ra_wl = (const float*)d_in[12];
    const float* c1ra_bl = (const float*)d_in[13];
    const float* c1ra_wr = (const float*)d_in[14];
    const float* c1rv_wl = (const float*)d_in[15];
    const float* c1rv_bl = (const float*)d_in[16];
    const float* c1rv_wr = (const float*)d_in[17];
    const float* c2ra_wl = (const float*)d_in[18];
    const float* c2ra_bl = (const float*)d_in[19];
    const float* c2ra_wr = (const float*)d_in[20];
    const float* c2rv_wl = (const float*)d_in[21];
    const float* c2rv_bl = (const float*)d_in[22];
    const float* c2rv_wr = (const float*)d_in[23];

    const long NH = (long)NU * Hc;
    __half* B0 = (__half*)d_ws;      // XU -> PRE_U2 -> HU2
    __half* B1 = B0 + NH;            // XR -> PRE_R2 -> HR2
    __half* B2 = B1 + NH;            // rec alias -> PRE_U -> HU
    __half* B3 = B2 + NH;            // PRE_R -> HR
    __half* TAh = B3 + NH;           // fp16 T, user rows
    __half* TBh = TAh + NH;          // fp16 T, recipe rows
    int* cnt   = (int*)(TBh + NH);   // [NTOT]
    int* base  = cnt + NTOT;         // [NTOT]
    int* bcnt  = base + NTOT;        // [NBKT]
    int* bbase = bcnt + NBKT;        // [NBKT+1]
    int* bcur  = bbase + NBKT + 1;   // [NBKT]
    int* adj   = bcur + NBKT;        // [2*EE]
    int* rec = (int*)B2;             // 16MB alias (B2 is 19.2MB), dead before first B2 write

    // ---- CSR build via bucketed counting sort ----
    hipMemsetAsync(bcnt, 0, (size_t)NBKT * sizeof(int), stream);
    bucket_count_kernel<<<NCHUNK, 256, 0, stream>>>(edge_index, bcnt);
    bucket_scan_kernel<<<1, 256, 0, stream>>>(bcnt, bbase, bcur);
    scatter_records_kernel<<<NCHUNK, 256, 0, stream>>>(edge_index, bcur, rec);
    build_adj_kernel<<<NBKT, 256, 0, stream>>>(rec, bbase, adj, base, cnt);

    // ---- encoders (MFMA, LDS weights, grid-stride): XU -> B0, XR -> B1 (fp16) ----
    encode_mfma<UF><<<1024, 256, 0, stream>>>(x_user, u_w, u_b, u_emb, user_nid, B0);
    encode_mfma<RF><<<1024, 256, 0, stream>>>(x_recipe, r_w, r_b, r_emb, rec_nid, B1);

    // ---- layer 1 dense pair (MFMA) ----
    dense2_mfma<<<2048, 256, 0, stream>>>(
        B0, c1ra_wl, c1rv_bl, c1rv_wr, TAh, B2,
        B1, c1rv_wl, c1ra_bl, c1ra_wr, TBh, B3);

    // ---- layer 1 gathers: HR = relu(PRE_R + mean TU1) (B3); HU = relu(PRE_U + mean TR1) (B2)
    gather8_kernel<<<2 * GB8, 256, 0, stream>>>(TAh, B3, TBh, B2, base, cnt, adj, 1);

    // ---- layer 2 dense pair (MFMA) ----
    dense2_mfma<<<2048, 256, 0, stream>>>(
        B2, c2ra_wl, c2rv_bl, c2rv_wr, TAh, B0,
        B3, c2rv_wl, c2ra_bl, c2ra_wr, TBh, B1);

    // ---- layer 2 gathers: HR2 = PRE_R2 + mean TU2 (B1); HU2 = PRE_U2 + mean TR2 (B0)
    gather8_kernel<<<2 * GB8, 256, 0, stream>>>(TAh, B1, TBh, B0, base, cnt, adj, 0);

    // ---- classifier: eli[0]=user -> HU2(B0), eli[1]=recipe -> HR2(B1) ----
    edge_dot_kernel<<<(ELc * 16) / 256, 256, 0, stream>>>(edge_label, B0, B1, (float*)d_out);
}